// Round 13
// baseline (619.125 us; speedup 1.0000x reference)
//
#include <hip/hip_runtime.h>
#include <hip/hip_bf16.h>
#include <math.h>

typedef __hip_bfloat16 bf16;
typedef __attribute__((ext_vector_type(8))) short bf16x8;
typedef __attribute__((ext_vector_type(4))) float f32x4;

#define Bc   32
#define Hc   56
#define Wcc  56
#define Nc   3136
#define Cpc  32
#define Cac  96
#define EPSc 1e-5f
#define SCALEc 0.28867513459481287f   /* 1/sqrt(12) */

__device__ __forceinline__ float gelu_f(float x) {
    return 0.5f * x * (1.0f + erff(x * 0.7071067811865475f));
}

// raw v_exp_f32 (2^x). Fallback keeps correctness if builtin is absent.
__device__ __forceinline__ float fast_exp2(float x) {
#if defined(__has_builtin)
#if __has_builtin(__builtin_amdgcn_exp2f)
    return __builtin_amdgcn_exp2f(x);
#else
    return exp2f(x);
#endif
#else
    return exp2f(x);
#endif
}

// ---------------- LN1: (B,N,128) -> xa fp32 (B,N,96) + xab bf16 + xc_img (B,32,56,56) fp32
__global__ __launch_bounds__(256) void ln1_kernel(const float* __restrict__ x,
        const float* __restrict__ g, const float* __restrict__ be,
        float* __restrict__ xa, bf16* __restrict__ xab, float* __restrict__ xc_img)
{
    int wv = threadIdx.x >> 6, lane = threadIdx.x & 63;
    int row = blockIdx.x * 4 + wv;
    if (row >= Bc * Nc) return;
    const float* xr = x + (size_t)row * 128;
    float x0 = xr[lane];
    float x1 = xr[lane + 64];
    float s = x0 + x1, q = x0 * x0 + x1 * x1;
    for (int o = 32; o; o >>= 1) { s += __shfl_xor(s, o); q += __shfl_xor(q, o); }
    float mean = s * (1.f / 128.f);
    float inv = rsqrtf(q * (1.f / 128.f) - mean * mean + EPSc);
    int b = row / Nc, n = row % Nc;
    {
        int c = lane;
        float y = (x0 - mean) * inv * g[c] + be[c];
        if (c < Cpc) xc_img[(size_t)(b * Cpc + c) * Nc + n] = y;
        else { xa[(size_t)row * Cac + (c - Cpc)] = y;
               xab[(size_t)row * Cac + (c - Cpc)] = __float2bfloat16(y); }
    }
    {
        int c = lane + 64;
        float y = (x1 - mean) * inv * g[c] + be[c];
        xa[(size_t)row * Cac + (c - Cpc)] = y;
        xab[(size_t)row * Cac + (c - Cpc)] = __float2bfloat16(y);
    }
}

// ---------------- Haar DWT (levels 0 and 1)
__global__ void dwt_kernel(const float* __restrict__ src, int cs, int h, int w,
                           int h2, int w2, float* __restrict__ sub)
{
    int t = blockIdx.x * blockDim.x + threadIdx.x;
    int total = Bc * 32 * h2 * w2;
    if (t >= total) return;
    int xx = t % w2; int r = t / w2;
    int yy = r % h2; r /= h2;
    int c = r & 31; int b = r >> 5;
    const float* sp = src + (size_t)cs * (b * 32 + c) * h * w;
    int y0 = yy * 2, x0 = xx * 2;
    bool xe = (x0 + 1 < w), ye = (y0 + 1 < h);
    float a  = sp[y0 * w + x0];
    float bb = xe ? sp[y0 * w + x0 + 1] : 0.f;
    float cc = ye ? sp[(y0 + 1) * w + x0] : 0.f;
    float dd = (xe && ye) ? sp[(y0 + 1) * w + x0 + 1] : 0.f;
    size_t pl = (size_t)h2 * w2;
    size_t ob = (size_t)(b * 128 + c * 4) * pl + yy * w2 + xx;
    sub[ob]          = ( a + bb + cc + dd) * 0.5f;
    sub[ob + pl]     = (-a - bb + cc + dd) * 0.5f;
    sub[ob + 2 * pl] = (-a + bb - cc + dd) * 0.5f;
    sub[ob + 3 * pl] = ( a - bb - cc + dd) * 0.5f;
}

// ---------------- FUSED DWT levels 2-4: one block per (b,c) plane; LL cascades
// through LDS. Bit-identical to three dwt_kernel launches.
__global__ __launch_bounds__(256) void dwt234_kernel(const float* __restrict__ S1,
        float* __restrict__ S2, float* __restrict__ S3, float* __restrict__ S4)
{
    __shared__ float ll[196];
    int bc = blockIdx.x; int b = bc >> 5, c = bc & 31;
    int t = threadIdx.x;
    const float* src = S1 + (size_t)(b * 128 + c * 4) * 196;   // LL plane of S1 (14x14)
    if (t < 196) ll[t] = src[t];
    __syncthreads();
    // level 2: 14x14 -> 7x7
    float l2 = 0.f;
    if (t < 49) {
        int yy = t / 7, xx = t % 7;
        int y0 = yy * 2, x0 = xx * 2;
        float a = ll[y0 * 14 + x0],       bb = ll[y0 * 14 + x0 + 1];
        float cc = ll[(y0 + 1) * 14 + x0], dd = ll[(y0 + 1) * 14 + x0 + 1];
        size_t ob = (size_t)(b * 128 + c * 4) * 49 + t;
        float vll = (a + bb + cc + dd) * 0.5f;
        S2[ob]       = vll;
        S2[ob + 49]  = (-a - bb + cc + dd) * 0.5f;
        S2[ob + 98]  = (-a + bb - cc + dd) * 0.5f;
        S2[ob + 147] = ( a - bb - cc + dd) * 0.5f;
        l2 = vll;
    }
    __syncthreads();
    if (t < 49) ll[t] = l2;
    __syncthreads();
    // level 3: 7x7 (odd, zero-pad) -> 4x4
    float l3 = 0.f;
    if (t < 16) {
        int yy = t >> 2, xx = t & 3;
        int y0 = yy * 2, x0 = xx * 2;
        bool xe = (x0 + 1 < 7), ye = (y0 + 1 < 7);
        float a  = ll[y0 * 7 + x0];
        float bb = xe ? ll[y0 * 7 + x0 + 1] : 0.f;
        float cc = ye ? ll[(y0 + 1) * 7 + x0] : 0.f;
        float dd = (xe && ye) ? ll[(y0 + 1) * 7 + x0 + 1] : 0.f;
        size_t ob = (size_t)(b * 128 + c * 4) * 16 + t;
        float vll = (a + bb + cc + dd) * 0.5f;
        S3[ob]      = vll;
        S3[ob + 16] = (-a - bb + cc + dd) * 0.5f;
        S3[ob + 32] = (-a + bb - cc + dd) * 0.5f;
        S3[ob + 48] = ( a - bb - cc + dd) * 0.5f;
        l3 = vll;
    }
    __syncthreads();
    if (t < 16) ll[t] = l3;
    __syncthreads();
    // level 4: 4x4 -> 2x2
    if (t < 4) {
        int yy = t >> 1, xx = t & 1;
        int y0 = yy * 2, x0 = xx * 2;
        float a = ll[y0 * 4 + x0],       bb = ll[y0 * 4 + x0 + 1];
        float cc = ll[(y0 + 1) * 4 + x0], dd = ll[(y0 + 1) * 4 + x0 + 1];
        size_t ob = (size_t)(b * 128 + c * 4) * 4 + t;
        S4[ob]      = ( a + bb + cc + dd) * 0.5f;
        S4[ob + 4]  = (-a - bb + cc + dd) * 0.5f;
        S4[ob + 8]  = (-a + bb - cc + dd) * 0.5f;
        S4[ob + 12] = ( a - bb - cc + dd) * 0.5f;
    }
}

// ---------------- merged wavelet depthwise 3x3 (all 5 levels, one launch)
template<int H>
__device__ __forceinline__ void dw3_body(int r, const float* __restrict__ src,
        const float* __restrict__ wt, const float* __restrict__ scale,
        float* __restrict__ dst)
{
    int x = r % H; int rr = r / H;
    int y = rr % H; rr /= H;
    int c = rr & 127;
    const float* sp = src + (r - x - y * H);
    float acc = 0.f;
    #pragma unroll
    for (int u = 0; u < 3; u++) {
        int yy = y + u - 1;
        if (yy < 0 || yy >= H) continue;
        #pragma unroll
        for (int v = 0; v < 3; v++) {
            int xx = x + v - 1;
            if (xx < 0 || xx >= H) continue;
            acc += sp[yy * H + xx] * wt[(u * 3 + v) * 128 + c];
        }
    }
    dst[r] = acc * scale[c];
}

__global__ void dw3x3_all_kernel(const float* __restrict__ sub, const float* __restrict__ wavw,
        const float* __restrict__ wavs, float* __restrict__ tt)
{
    int t = blockIdx.x * blockDim.x + threadIdx.x;
    if (t < 3211264)      dw3_body<28>(t,           sub,           wavw,        wavs,       tt);
    else if (t < 4014080) dw3_body<14>(t - 3211264, sub + 3211264, wavw + 1152, wavs + 128, tt + 3211264);
    else if (t < 4214784) dw3_body<7> (t - 4014080, sub + 4014080, wavw + 2304, wavs + 256, tt + 4014080);
    else if (t < 4280320) dw3_body<4> (t - 4214784, sub + 4214784, wavw + 3456, wavs + 384, tt + 4214784);
    else if (t < 4296704) dw3_body<2> (t - 4280320, sub + 4280320, wavw + 4608, wavs + 512, tt + 4280320);
}

// ---------------- FUSED IDWT levels 4..2: one block per (b,c); recon cascades
// through LDS; writes the 14x14 recon (RA equivalent) for level-1 idwt.
__global__ __launch_bounds__(256) void idwt432_kernel(const float* __restrict__ T4,
        const float* __restrict__ T3, const float* __restrict__ T2,
        float* __restrict__ out14)
{
    __shared__ float rec[196];
    int bc = blockIdx.x; int b = bc >> 5, c = bc & 31;
    int t = threadIdx.x;
    // level 4: T4 (2x2 planes) -> 4x4
    float v4 = 0.f;
    if (t < 16) {
        int y = t >> 2, x = t & 3;
        int y2 = y >> 1, x2 = x >> 1;
        size_t base = (size_t)(b * 128 + c * 4) * 4 + y2 * 2 + x2;
        float ll = T4[base];
        float lh = T4[base + 4], hl = T4[base + 8], hh = T4[base + 12];
        float v;
        if ((y & 1) == 0) v = ((x & 1) == 0) ? (ll - lh - hl + hh) : (ll - lh + hl - hh);
        else              v = ((x & 1) == 0) ? (ll + lh - hl - hh) : (ll + lh + hl + hh);
        v4 = v * 0.5f;
    }
    if (t < 16) rec[t] = v4;
    __syncthreads();
    // level 3: T3 (4x4 planes) + rec -> 7x7 (crop from 8x8)
    float v3 = 0.f;
    if (t < 49) {
        int y = t / 7, x = t % 7;
        int y2 = y >> 1, x2 = x >> 1;
        size_t base = (size_t)(b * 128 + c * 4) * 16 + y2 * 4 + x2;
        float ll = T3[base] + rec[y2 * 4 + x2];
        float lh = T3[base + 16], hl = T3[base + 32], hh = T3[base + 48];
        float v;
        if ((y & 1) == 0) v = ((x & 1) == 0) ? (ll - lh - hl + hh) : (ll - lh + hl - hh);
        else              v = ((x & 1) == 0) ? (ll + lh - hl - hh) : (ll + lh + hl + hh);
        v3 = v * 0.5f;
    }
    __syncthreads();
    if (t < 49) rec[t] = v3;
    __syncthreads();
    // level 2: T2 (7x7 planes) + rec -> 14x14, write global
    if (t < 196) {
        int y = t / 14, x = t % 14;
        int y2 = y >> 1, x2 = x >> 1;
        size_t base = (size_t)(b * 128 + c * 4) * 49 + y2 * 7 + x2;
        float ll = T2[base] + rec[y2 * 7 + x2];
        float lh = T2[base + 49], hl = T2[base + 98], hh = T2[base + 147];
        float v;
        if ((y & 1) == 0) v = ((x & 1) == 0) ? (ll - lh - hl + hh) : (ll - lh + hl - hh);
        else              v = ((x & 1) == 0) ? (ll + lh - hl - hh) : (ll + lh + hl + hh);
        out14[(size_t)(b * 32 + c) * 196 + t] = v * 0.5f;
    }
}

// ---------------- Haar IDWT (+ll add, crop) — level 1
__global__ void idwt_kernel(const float* __restrict__ tl, const float* __restrict__ nxt,
        float* __restrict__ outp, int h2, int w2, int ho, int wo)
{
    int t = blockIdx.x * blockDim.x + threadIdx.x;
    int total = Bc * 32 * ho * wo;
    if (t >= total) return;
    int x = t % wo; int r = t / wo;
    int y = r % ho; r /= ho;
    int c = r & 31; int b = r >> 5;
    int y2 = y >> 1, x2 = x >> 1;
    size_t pl = (size_t)h2 * w2;
    size_t base = (size_t)(b * 128 + c * 4) * pl + y2 * w2 + x2;
    float ll = tl[base];
    if (nxt) ll += nxt[(size_t)(b * 32 + c) * pl + y2 * w2 + x2];
    float lh = tl[base + pl], hl = tl[base + 2 * pl], hh = tl[base + 3 * pl];
    float v;
    if ((y & 1) == 0) v = ((x & 1) == 0) ? (ll - lh - hl + hh) : (ll - lh + hl - hh);
    else              v = ((x & 1) == 0) ? (ll + lh - hl - hh) : (ll + lh + hl + hh);
    outp[t] = v * 0.5f;
}

// ---------------- fused idwt level-0 + base depthwise conv -> bf16 NHWC
__global__ void idwt_dwbase_kernel(const float* __restrict__ tl, const float* __restrict__ nxt,
        const float* __restrict__ src, const float* __restrict__ wt,
        const float* __restrict__ scale, const float* __restrict__ bias,
        bf16* __restrict__ dst_nhwc)
{
    int t = blockIdx.x * blockDim.x + threadIdx.x;
    if (t >= Bc * 32 * Nc) return;
    int x = t % Wcc; int r = t / Wcc;
    int y = r % Hc; r /= Hc;
    int c = r & 31; int b = r >> 5;
    int y2 = y >> 1, x2 = x >> 1;
    const size_t pl = 784;
    size_t base = (size_t)(b * 128 + c * 4) * pl + y2 * 28 + x2;
    float ll = tl[base] + nxt[(size_t)(b * 32 + c) * pl + y2 * 28 + x2];
    float lh = tl[base + pl], hl = tl[base + 2 * pl], hh = tl[base + 3 * pl];
    float v;
    if ((y & 1) == 0) v = ((x & 1) == 0) ? (ll - lh - hl + hh) : (ll - lh + hl - hh);
    else              v = ((x & 1) == 0) ? (ll + lh - hl - hh) : (ll + lh + hl + hh);
    float recon = v * 0.5f;
    const float* sp = src + (t - x - y * Wcc);
    float acc = 0.f;
    #pragma unroll
    for (int u = 0; u < 3; u++) {
        int yy = y + u - 1;
        if (yy < 0 || yy >= Hc) continue;
        #pragma unroll
        for (int vv2 = 0; vv2 < 3; vv2++) {
            int xx = x + vv2 - 1;
            if (xx < 0 || xx >= Wcc) continue;
            acc += sp[yy * Wcc + xx] * wt[(u * 3 + vv2) * 32 + c];
        }
    }
    acc = (acc + bias[c]) * scale[c] + recon;
    dst_nhwc[(((size_t)b * Hc + y) * Wcc + x) * 32 + c] = __float2bfloat16(acc);
}

// ---------------- merged weight prep (plain transposes; no permutation)
__global__ void wprep_kernel(const float* __restrict__ qw, const float* __restrict__ kv1w,
        const float* __restrict__ kv2w, const float* __restrict__ pw,
        const float* __restrict__ f1w, const float* __restrict__ f2w,
        const float* __restrict__ cpw, bf16* __restrict__ qwt, bf16* __restrict__ kv1wt,
        bf16* __restrict__ kv2wt, bf16* __restrict__ pwt, bf16* __restrict__ w1t,
        bf16* __restrict__ w2t, bf16* __restrict__ cpwt)
{
    int t = blockIdx.x * blockDim.x + threadIdx.x;
    if (t < 9216) {
        int n = t % 96, k = t / 96;
        qwt[n * 96 + k] = __float2bfloat16(qw[t]);
    } else if (t < 18432) {
        int u = t - 9216; int n = u % 96, k = u / 96;
        kv1wt[n * 96 + k] = __float2bfloat16(kv1w[u]);
    } else if (t < 27648) {
        int u = t - 18432; int n = u % 96, k = u / 96;
        kv2wt[n * 96 + k] = __float2bfloat16(kv2w[u]);
    } else if (t < 44032) {
        int u = t - 27648; int n = u % 128, k = u / 128;
        pwt[n * 128 + k] = __float2bfloat16(pw[u]);
    } else if (t < 109568) {
        int u = t - 44032; int n = u % 512, k = u / 512;
        w1t[(size_t)n * 128 + k] = __float2bfloat16(f1w[u]);
    } else if (t < 175104) {
        int u = t - 109568; int n = u % 128, k = u / 128;
        w2t[(size_t)n * 512 + k] = __float2bfloat16(f2w[u]);
    } else if (t < 184320) {
        int u = t - 175104; int co = u / 288, k = u % 288;
        cpwt[u] = __float2bfloat16(cpw[k * 32 + co]);
    }
}

// ---------------- cp2d implicit-GEMM MFMA + FUSED cn (LN over 32 ch + gelu)
__global__ __launch_bounds__(256) void cp2d_cn_kernel(const bf16* __restrict__ src,
        const bf16* __restrict__ wtc, const float* __restrict__ bias,
        const float* __restrict__ cnw, const float* __restrict__ cnb,
        bf16* __restrict__ attn_cat)
{
    __shared__ unsigned short in_s[10 * 400];
    __shared__ unsigned short w_s[32 * 296];
    int tid = threadIdx.x;
    int b = blockIdx.y;
    int ty = blockIdx.x / 7, tx = blockIdx.x % 7;
    for (int idx = tid; idx < 1152; idx += 256) {
        int co = idx / 36, j8 = (idx % 36) * 8;
        *(int4*)&w_s[co * 296 + j8] = *(const int4*)(wtc + co * 288 + j8);
    }
    {
        int idx = tid;
        if (idx < 200) {
            int cell = idx >> 1, half = idx & 1;
            int dy = cell / 10, dx = cell % 10;
            int gy = ty * 8 - 1 + dy, gx = tx * 8 - 1 + dx;
            int4 v0 = make_int4(0, 0, 0, 0), v1 = v0;
            if (gy >= 0 && gy < 56 && gx >= 0 && gx < 56) {
                const int4* gp = (const int4*)(src + ((((size_t)b * 56 + gy) * 56 + gx) * 32 + half * 16));
                v0 = gp[0]; v1 = gp[1];
            }
            *(int4*)&in_s[dy * 400 + dx * 40 + half * 16] = v0;
            *(int4*)&in_s[dy * 400 + dx * 40 + half * 16 + 8] = v1;
        }
    }
    __syncthreads();
    int wave = tid >> 6, lane = tid & 63;
    int ml = lane & 15, qd = lane >> 4;
    int m = wave * 16 + ml;
    int ly = m >> 3, lx = m & 7;
    f32x4 acc0 = {0.f, 0.f, 0.f, 0.f}, acc1 = {0.f, 0.f, 0.f, 0.f};
    #pragma unroll
    for (int u = 0; u < 3; u++)
    #pragma unroll
    for (int v = 0; v < 3; v++) {
        bf16x8 af = *(const bf16x8*)&in_s[(ly + u) * 400 + (lx + v) * 40 + qd * 8];
        int k = (u * 3 + v) * 32 + qd * 8;
        bf16x8 b0 = *(const bf16x8*)&w_s[ml * 296 + k];
        bf16x8 b1 = *(const bf16x8*)&w_s[(16 + ml) * 296 + k];
        acc0 = __builtin_amdgcn_mfma_f32_16x16x32_bf16(af, b0, acc0, 0, 0, 0);
        acc1 = __builtin_amdgcn_mfma_f32_16x16x32_bf16(af, b1, acc1, 0, 0, 0);
    }
    float bia0 = bias[ml], bia1 = bias[16 + ml];
    float g0 = cnw[ml], g1 = cnw[16 + ml];
    float be0 = cnb[ml], be1 = cnb[16 + ml];
    #pragma unroll
    for (int r = 0; r < 4; r++) {
        float c0 = acc0[r] + bia0;
        float c1 = acc1[r] + bia1;
        float s = c0 + c1, q = c0 * c0 + c1 * c1;
        #pragma unroll
        for (int o = 8; o; o >>= 1) { s += __shfl_xor(s, o); q += __shfl_xor(q, o); }
        float mean = s * (1.f / 32.f);
        float inv = rsqrtf(q * (1.f / 32.f) - mean * mean + EPSc);
        int mr = wave * 16 + qd * 4 + r;
        int ry = ty * 8 + (mr >> 3), rx = tx * 8 + (mr & 7);
        bf16* op = attn_cat + ((size_t)b * Nc + ry * 56 + rx) * 128 + 96;
        op[ml]      = __float2bfloat16(gelu_f((c0 - mean) * inv * g0 + be0));
        op[16 + ml] = __float2bfloat16(gelu_f((c1 - mean) * inv * g1 + be1));
    }
}

// ---------------- merged sr: both depthwise reductions in one launch
template<int KS, int LD>
__device__ __forceinline__ void sr_body(int t, const float* __restrict__ xa,
        const float* __restrict__ wt, const float* __restrict__ bias,
        float* __restrict__ outp)
{
    int c = t % Cac; int r = t / Cac;
    int j = r % LD; r /= LD;
    int i = r % LD; int b = r / LD;
    float acc = bias[c];
    for (int u = 0; u < KS; u++)
        for (int v = 0; v < KS; v++)
            acc += xa[(size_t)(b * Nc + (i * KS + u) * Wcc + (j * KS + v)) * Cac + c]
                 * wt[(u * KS + v) * Cac + c];
    outp[t] = acc;
}

__global__ void sr_all_kernel(const float* __restrict__ xa,
        const float* __restrict__ sr1w, const float* __restrict__ sr1b, float* __restrict__ x1p,
        const float* __restrict__ sr2w, const float* __restrict__ sr2b, float* __restrict__ x2p)
{
    int t = blockIdx.x * blockDim.x + threadIdx.x;
    if (t < 150528) sr_body<8, 7>(t, xa, sr1w, sr1b, x1p);
    else {
        int u = t - 150528;
        if (u < 602112) sr_body<4, 14>(u, xa, sr2w, sr2b, x2p);
    }
}

// ---------------- merged LN over 96 + gelu -> bf16 (both branches, one launch)
__global__ __launch_bounds__(256) void ln96_all_kernel(
        const float* __restrict__ s1, const float* __restrict__ g1,
        const float* __restrict__ b1, bf16* __restrict__ d1,
        const float* __restrict__ s2, const float* __restrict__ g2,
        const float* __restrict__ b2, bf16* __restrict__ d2)
{
    int wv = threadIdx.x >> 6, lane = threadIdx.x & 63;
    int row = blockIdx.x * 4 + wv;
    const float* sp; const float* g; const float* be; bf16* dst; int r;
    if (row < 1568)      { sp = s1; g = g1; be = b1; dst = d1; r = row; }
    else if (row < 7840) { sp = s2; g = g2; be = b2; dst = d2; r = row - 1568; }
    else return;
    sp += (size_t)r * 96;
    float x0 = sp[lane];
    float x1 = (lane < 32) ? sp[64 + lane] : 0.f;
    float s = x0 + x1, q = x0 * x0 + x1 * x1;
    for (int o = 32; o; o >>= 1) { s += __shfl_xor(s, o); q += __shfl_xor(q, o); }
    float mean = s * (1.f / 96.f);
    float inv = rsqrtf(q * (1.f / 96.f) - mean * mean + EPSc);
    dst[(size_t)r * 96 + lane] =
        __float2bfloat16(gelu_f((x0 - mean) * inv * g[lane] + be[lane]));
    if (lane < 32)
        dst[(size_t)r * 96 + 64 + lane] =
            __float2bfloat16(gelu_f((x1 - mean) * inv * g[64 + lane] + be[64 + lane]));
}

// ---------------- MFMA GEMM (MR=1, templated K-depth BK). OMODE: 0 = fp32
// row-major, 1 = bf16 row-major, 2 = fp32 head-major Q layout (B,8,N,12)
template<int NF, int BK, bool GELU, bool RES, int OMODE>
__global__ __launch_bounds__(256) void gemm_kernel(const bf16* __restrict__ A,
        const bf16* __restrict__ Wt, const float* __restrict__ bias,
        const float* __restrict__ res, void* __restrict__ outp,
        int M, int K, int Nt)
{
    constexpr int TN = 16 * NF;
    __shared__ unsigned short As[64][BK + 8];
    __shared__ unsigned short Bs[TN][BK + 8];
    int tid = threadIdx.x;
    int wave = tid >> 6, lane = tid & 63;
    int m0 = blockIdx.y * 64, n0 = blockIdx.x * TN;
    f32x4 acc[NF];
    #pragma unroll
    for (int f = 0; f < NF; f++) acc[f] = (f32x4){0.f, 0.f, 0.f, 0.f};

    int ar = tid >> 2, ac = (tid & 3) << 3;
    int ml = wave * 16 + (lane & 15);
    int qd = lane >> 4;

    for (int k0 = 0; k0 < K; k0 += BK) {
        #pragma unroll
        for (int i = 0; i < BK / 32; i++) {
            int cc = ac + i * 32;
            int4 av = make_int4(0, 0, 0, 0);
            if (m0 + ar < M) av = *(const int4*)(A + (size_t)(m0 + ar) * K + k0 + cc);
            *(int4*)&As[ar][cc] = av;
        }
        for (int idx = tid; idx < TN * (BK / 8); idx += 256) {
            int br = idx / (BK / 8), bc = (idx % (BK / 8)) * 8;
            *(int4*)&Bs[br][bc] = *(const int4*)(Wt + (size_t)(n0 + br) * K + k0 + bc);
        }
        __syncthreads();
        #pragma unroll
        for (int kk = 0; kk < BK / 32; kk++) {
            bf16x8 af = *(const bf16x8*)&As[ml][kk * 32 + qd * 8];
            #pragma unroll
            for (int f = 0; f < NF; f++) {
                bf16x8 bfv = *(const bf16x8*)&Bs[f * 16 + (lane & 15)][kk * 32 + qd * 8];
                acc[f] = __builtin_amdgcn_mfma_f32_16x16x32_bf16(af, bfv, acc[f], 0, 0, 0);
            }
        }
        __syncthreads();
    }
    #pragma unroll
    for (int f = 0; f < NF; f++) {
        int n = n0 + f * 16 + (lane & 15);
        #pragma unroll
        for (int r = 0; r < 4; r++) {
            int m = m0 + wave * 16 + qd * 4 + r;
            if (m >= M) continue;
            float v = acc[f][r];
            if (bias) v += bias[n];
            if (GELU) v = gelu_f(v);
            if (RES)  v += res[(size_t)m * Nt + n];
            if (OMODE == 1)
                ((bf16*)outp)[(size_t)m * Nt + n] = __float2bfloat16(v);
            else if (OMODE == 2) {
                int b = m / Nc, nn = m - b * Nc;
                int h = n / 12, d = n - h * 12;
                ((float*)outp)[(((size_t)(b * 8 + h)) * Nc + nn) * 12 + d] = v;
            } else
                ((float*)outp)[(size_t)m * Nt + n] = v;
        }
    }
}

// ---------------- proj GEMM (K=128, TN=128 full rows) + bias + residual + FUSED LN2.
__global__ __launch_bounds__(256) void proj_ln_kernel(const bf16* __restrict__ A,
        const bf16* __restrict__ Wt, const float* __restrict__ bias,
        const float* __restrict__ res, const float* __restrict__ g,
        const float* __restrict__ be, float* __restrict__ xres, bf16* __restrict__ xnb)
{
    __shared__ unsigned short As[64][72];
    __shared__ unsigned short Bs[128][72];
    int tid = threadIdx.x;
    int wave = tid >> 6, lane = tid & 63;
    int m0 = blockIdx.x * 64;
    f32x4 acc[8];
    #pragma unroll
    for (int f = 0; f < 8; f++) acc[f] = (f32x4){0.f, 0.f, 0.f, 0.f};

    int ar = tid >> 2, ac = (tid & 3) << 3;
    int ml = lane & 15, qd = lane >> 4;
    int mlw = wave * 16 + ml;

    for (int k0 = 0; k0 < 128; k0 += 64) {
        #pragma unroll
        for (int i = 0; i < 2; i++) {
            int cc = ac + i * 32;
            *(int4*)&As[ar][cc] = *(const int4*)(A + (size_t)(m0 + ar) * 128 + k0 + cc);
        }
        for (int idx = tid; idx < 1024; idx += 256) {
            int br = idx >> 3, bc = (idx & 7) * 8;
            *(int4*)&Bs[br][bc] = *(const int4*)(Wt + (size_t)br * 128 + k0 + bc);
        }
        __syncthreads();
        #pragma unroll
        for (int kk = 0; kk < 2; kk++) {
            bf16x8 af = *(const bf16x8*)&As[mlw][kk * 32 + qd * 8];
            #pragma unroll
            for (int f = 0; f < 8; f++) {
                bf16x8 bfv = *(const bf16x8*)&Bs[f * 16 + ml][kk * 32 + qd * 8];
                acc[f] = __builtin_amdgcn_mfma_f32_16x16x32_bf16(af, bfv, acc[f], 0, 0, 0);
            }
        }
        __syncthreads();
    }
    float bia[8], gg[8], bb[8];
    #pragma unroll
    for (int f = 0; f < 8; f++) {
        int n = f * 16 + ml;
        bia[f] = bias[n]; gg[f] = g[n]; bb[f] = be[n];
    }
    #pragma unroll
    for (int r = 0; r < 4; r++) {
        int m = m0 + wave * 16 + qd * 4 + r;
        float vv[8];
        float s = 0.f, q = 0.f;
        #pragma unroll
        for (int f = 0; f < 8; f++) {
            int n = f * 16 + ml;
            float v = acc[f][r] + bia[f] + res[(size_t)m * 128 + n];
            vv[f] = v; s += v; q += v * v;
        }
        #pragma unroll
        for (int o = 8; o; o >>= 1) { s += __shfl_xor(s, o); q += __shfl_xor(q, o); }
        float mean = s * (1.f / 128.f);
        float inv = rsqrtf(q * (1.f / 128.f) - mean * mean + EPSc);
        #pragma unroll
        for (int f = 0; f < 8; f++) {
            int n = f * 16 + ml;
            xres[(size_t)m * 128 + n] = vv[f];
            xnb[(size_t)m * 128 + n] =
                __float2bfloat16((vv[f] - mean) * inv * gg[f] + bb[f]);
        }
    }
}

// ---------------- attention body: round-1 proven shape + raw v_exp_f32 (125us):
// fp32 K/V in LDS, 1 query/thread, branchless single-pass softmax.
template<int L>
__device__ __forceinline__ void attn_body(const float* __restrict__ qh,
        const float* __restrict__ kv, int hl, int h, int b,
        float* kb, float* vb, bf16* __restrict__ attn_cat)
{
    for (int idx = threadIdx.x; idx < L * 3; idx += 256) {
        int l = idx / 3, f = idx % 3;
        const float4* kp = (const float4*)(kv + (size_t)(b * L + l) * 96 + hl * 12) + f;
        float4 kk = kp[0];
        float4 vv = kp[12];
        *(float4*)&kb[l * 12 + f * 4] = kk;
        *(float4*)&vb[l * 12 + f * 4] = vv;
    }
    int n = blockIdx.x * 256 + threadIdx.x;
    bool act = (n < Nc);
    int nn = act ? n : (Nc - 1);
    const float4* qp = (const float4*)(qh + (((size_t)(b * 8 + h)) * Nc + nn) * 12);
    float4 q0 = qp[0], q1 = qp[1], q2 = qp[2];
    const float PRE = SCALEc * 1.4426950408889634f;   /* scale * log2(e) */
    q0.x *= PRE; q0.y *= PRE; q0.z *= PRE; q0.w *= PRE;
    q1.x *= PRE; q1.y *= PRE; q1.z *= PRE; q1.w *= PRE;
    q2.x *= PRE; q2.y *= PRE; q2.z *= PRE; q2.w *= PRE;
    __syncthreads();

    float den = 0.f;
    float o[12];
    #pragma unroll
    for (int d = 0; d < 12; d++) o[d] = 0.f;

    #pragma unroll 4
    for (int l = 0; l < L; l++) {
        const float4 k0 = *(const float4*)&kb[l * 12];
        const float4 k1 = *(const float4*)&kb[l * 12 + 4];
        const float4 k2 = *(const float4*)&kb[l * 12 + 8];
        float s0 = q0.x * k0.x + q0.y * k0.y + q0.z * k0.z + q0.w * k0.w;
        float s1 = q1.x * k1.x + q1.y * k1.y + q1.z * k1.z + q1.w * k1.w;
        float s2 = q2.x * k2.x + q2.y * k2.y + q2.z * k2.z + q2.w * k2.w;
        float e = fast_exp2(s0 + s1 + s2);
        den += e;
        const float4 v0 = *(const float4*)&vb[l * 12];
        const float4 v1 = *(const float4*)&vb[l * 12 + 4];
        const float4 v2 = *(const float4*)&vb[l * 12 + 8];
        o[0] += e * v0.x; o[1]  += e * v0.y; o[2]  += e * v0.z; o[3]  += e * v0.w;
        o[4] += e * v1.x; o[5]  += e * v1.y; o[6]  += e * v1.z; o[7]  += e * v1.w;
        o[8] += e * v2.x; o[9]  += e * v2.y; o[10] += e * v2.z; o[11] += e * v2.w;
    }
    if (act) {
        float rden = 1.f / den;
        bf16* op = attn_cat + (size_t)(b * Nc + n) * 128 + h * 12;
        #pragma unroll
        for (int d = 0; d < 12; d++) op[d] = __float2bfloat16(o[d] * rden);
    }
}

__global__ __launch_bounds__(256) void attn_kernel(const float* __restrict__ qh,
        const float* __restrict__ kv1, const float* __restrict__ kv2,
        bf16* __restrict__ attn_cat)
{
    __shared__ float kb[196 * 12];
    __shared__ float vb[196 * 12];
    int h = blockIdx.y, b = blockIdx.z;
    if (h < 4) attn_body<49> (qh, kv1, h,     h, b, kb, vb, attn_cat);
    else       attn_body<196>(qh, kv2, h - 4, h, b, kb, vb, attn_cat);
}

extern "C" void kernel_launch(void* const* d_in, const int* in_sizes, int n_in,
                              void* d_out, int out_size, void* d_ws, size_t ws_size,
                              hipStream_t stream)
{
    const float* x    = (const float*)d_in[0];
    const float* ln1w = (const float*)d_in[3];
    const float* ln1b = (const float*)d_in[4];
    const float* ln2w = (const float*)d_in[5];
    const float* ln2b = (const float*)d_in[6];
    const float* qw   = (const float*)d_in[7];
    const float* kv1w = (const float*)d_in[8];
    const float* kv2w = (const float*)d_in[9];
    const float* sr1w = (const float*)d_in[10];
    const float* sr1b = (const float*)d_in[11];
    const float* sr2w = (const float*)d_in[12];
    const float* sr2b = (const float*)d_in[13];
    const float* an1w = (const float*)d_in[14];
    const float* an1b = (const float*)d_in[15];
    const float* an2w = (const float*)d_in[16];
    const float* an2b = (const float*)d_in[17];
    const float* wbw  = (const float*)d_in[18];
    const float* wbb  = (const float*)d_in[19];
    const float* wbs  = (const float*)d_in[20];
    const float* wavw = (const float*)d_in[21];
    const float* wavs = (const float*)d_in[22];
    const float* cpw  = (const float*)d_in[23];
    const float* cpb  = (const float*)d_in[24];
    const float* cnw  = (const float*)d_in[25];
    const float* cnb  = (const float*)d_in[26];
    const float* pw   = (const float*)d_in[27];
    const float* pb   = (const float*)d_in[28];
    const float* f1w  = (const float*)d_in[29];
    const float* f1b  = (const float*)d_in[30];
    const float* f2w  = (const float*)d_in[31];
    const float* f2b  = (const float*)d_in[32];
    float* dout = (float*)d_out;
    float* ws = (float*)d_ws;

    float* XA    = ws;                      // 9,633,792
    float* QB    = ws + 9633792;            // head-major Q (B,8,N,12)
    float* XRES  = ws;                      // overlay
    bf16*  XNb   = (bf16*)(ws + 12845056);
    bf16*  XAb   = (bf16*)(ws + 19267584);
    bf16*  ACATb = (bf16*)(ws + 24084480);
    float* XCI   = ws + 30507008;
    float* SUB   = ws + 33718272;
    float* TT    = ws + 38014976;
    float* RA    = ws + 42311680;
    float* RB    = ws + 45522944;
    float* X1P   = ws + 48734208;
    float* X2P   = ws + 48884736;
    bf16*  X1Bb  = (bf16*)(ws + 49486848);
    bf16*  X2Bb  = (bf16*)(ws + 49562112);
    float* KV1   = ws + 49863168;
    float* KV2   = ws + 50013696;
    bf16*  WTB   = (bf16*)(ws + 50615808);
    bf16*  qwt   = WTB;
    bf16*  kv1wt = WTB + 9216;
    bf16*  kv2wt = WTB + 18432;
    bf16*  pwt   = WTB + 27648;
    bf16*  w1t   = WTB + 44032;
    bf16*  w2t   = WTB + 109568;
    bf16*  cpwt  = WTB + 175104;
    bf16*  Hb    = (bf16*)(ws + 24084480);  // overlays ACATb (dead after proj)
    bf16*  CIMGb = (bf16*)SUB;
    float* S0 = SUB;            float* T0 = TT;
    float* S1 = SUB + 3211264;  float* T1 = TT + 3211264;
    float* S2 = SUB + 4014080;  float* T2 = TT + 4014080;
    float* S3 = SUB + 4214784;  float* T3 = TT + 4214784;
    float* S4 = SUB + 4280320;  float* T4 = TT + 4280320;

    // 0. weight preps (single merged launch)
    wprep_kernel<<<720, 256, 0, stream>>>(qw, kv1w, kv2w, pw, f1w, f2w, cpw,
                                          qwt, kv1wt, kv2wt, pwt, w1t, w2t, cpwt);

    // 1. LN1
    ln1_kernel<<<25088, 256, 0, stream>>>(x, ln1w, ln1b, XA, XAb, XCI);

    // 2. DWT: levels 0,1 elementwise; levels 2-4 fused per-plane
    dwt_kernel<<<3136, 256, 0, stream>>>(XCI, 1, 56, 56, 28, 28, S0);
    dwt_kernel<<<784,  256, 0, stream>>>(S0, 4, 28, 28, 14, 14, S1);
    dwt234_kernel<<<1024, 256, 0, stream>>>(S1, S2, S3, S4);

    // 3. ALL wavelet depthwise convs in one launch
    dw3x3_all_kernel<<<16784, 256, 0, stream>>>(SUB, wavw, wavs, TT);

    // 4. IDWT: levels 4-2 fused (writes 14x14 recon into RA); level 1 separate
    idwt432_kernel<<<1024, 256, 0, stream>>>(T4, T3, T2, RA);
    idwt_kernel<<<3136, 256, 0, stream>>>(T1, RA, RB, 14, 14, 28, 28);

    // 5. fused idwt level-0 + base depthwise conv -> bf16 NHWC
    idwt_dwbase_kernel<<<12544, 256, 0, stream>>>(T0, RB, XCI, wbw, wbs, wbb, CIMGb);

    // 6. cp2d implicit-GEMM MFMA + fused cn -> ACATb[96:128]
    cp2d_cn_kernel<<<dim3(49, 32), 256, 0, stream>>>(CIMGb, cpwt, cpb, cnw, cnb, ACATb);

    // 7. merged spatial reductions
    sr_all_kernel<<<2940, 256, 0, stream>>>(XA, sr1w, sr1b, X1P, sr2w, sr2b, X2P);

    // 8. merged LN96 + gelu -> bf16
    ln96_all_kernel<<<1960, 256, 0, stream>>>(X1P, an1w, an1b, X1Bb,
                                              X2P, an2w, an2b, X2Bb);

    // 9. q / kv GEMMs (q -> head-major)
    gemm_kernel<6,32,false,false,2><<<dim3(1, 1568), 256, 0, stream>>>(XAb,  qwt,   nullptr, nullptr, QB,  100352, 96, 96);
    gemm_kernel<6,32,false,false,0><<<dim3(1, 25),   256, 0, stream>>>(X1Bb, kv1wt, nullptr, nullptr, KV1, 1568,   96, 96);
    gemm_kernel<6,32,false,false,0><<<dim3(1, 98),   256, 0, stream>>>(X2Bb, kv2wt, nullptr, nullptr, KV2, 6272,   96, 96);

    // 10. merged attention -> ACATb[0:96]
    attn_kernel<<<dim3(13, 8, 32), 256, 0, stream>>>(QB, KV1, KV2, ACATb);

    // 11. proj + bias + residual(x) + FUSED LN2 -> XRES fp32 + XNb bf16
    proj_ln_kernel<<<1568, 256, 0, stream>>>(ACATb, pwt, pb, x, ln2w, ln2b, XRES, XNb);

    // 12. fc1 + bias + gelu -> Hb bf16  (BK=64; round-10 proven)
    gemm_kernel<4,64,true,false,1><<<dim3(8, 1568), 256, 0, stream>>>(XNb, w1t, f1b, nullptr, Hb, 100352, 128, 512);

    // 13. fc2 + bias + residual(XRES) -> d_out fp32  (NF=8 single n-block: Hb read once)
    gemm_kernel<8,64,false,true,0><<<dim3(1, 1568), 256, 0, stream>>>(Hb, w2t, f2b, XRES, dout, 100352, 512, 128);
}

// Round 14
// 592.432 us; speedup vs baseline: 1.0451x; 1.0451x over previous
//
#include <hip/hip_runtime.h>
#include <hip/hip_bf16.h>
#include <math.h>

typedef __hip_bfloat16 bf16;
typedef __attribute__((ext_vector_type(8))) short bf16x8;
typedef __attribute__((ext_vector_type(4))) float f32x4;

#define Bc   32
#define Hc   56
#define Wcc  56
#define Nc   3136
#define Cpc  32
#define Cac  96
#define EPSc 1e-5f
#define SCALEc 0.28867513459481287f   /* 1/sqrt(12) */

__device__ __forceinline__ float gelu_f(float x) {
    return 0.5f * x * (1.0f + erff(x * 0.7071067811865475f));
}

// raw v_exp_f32 (2^x). Fallback keeps correctness if builtin is absent.
__device__ __forceinline__ float fast_exp2(float x) {
#if defined(__has_builtin)
#if __has_builtin(__builtin_amdgcn_exp2f)
    return __builtin_amdgcn_exp2f(x);
#else
    return exp2f(x);
#endif
#else
    return exp2f(x);
#endif
}

// ---------------- LN1: (B,N,128) -> xa fp32 (B,N,96) + xab bf16 + xc_img (B,32,56,56) fp32
__global__ __launch_bounds__(256) void ln1_kernel(const float* __restrict__ x,
        const float* __restrict__ g, const float* __restrict__ be,
        float* __restrict__ xa, bf16* __restrict__ xab, float* __restrict__ xc_img)
{
    int wv = threadIdx.x >> 6, lane = threadIdx.x & 63;
    int row = blockIdx.x * 4 + wv;
    if (row >= Bc * Nc) return;
    const float* xr = x + (size_t)row * 128;
    float x0 = xr[lane];
    float x1 = xr[lane + 64];
    float s = x0 + x1, q = x0 * x0 + x1 * x1;
    for (int o = 32; o; o >>= 1) { s += __shfl_xor(s, o); q += __shfl_xor(q, o); }
    float mean = s * (1.f / 128.f);
    float inv = rsqrtf(q * (1.f / 128.f) - mean * mean + EPSc);
    int b = row / Nc, n = row % Nc;
    {
        int c = lane;
        float y = (x0 - mean) * inv * g[c] + be[c];
        if (c < Cpc) xc_img[(size_t)(b * Cpc + c) * Nc + n] = y;
        else { xa[(size_t)row * Cac + (c - Cpc)] = y;
               xab[(size_t)row * Cac + (c - Cpc)] = __float2bfloat16(y); }
    }
    {
        int c = lane + 64;
        float y = (x1 - mean) * inv * g[c] + be[c];
        xa[(size_t)row * Cac + (c - Cpc)] = y;
        xab[(size_t)row * Cac + (c - Cpc)] = __float2bfloat16(y);
    }
}

// ---------------- Haar DWT (levels 0 and 1)
__global__ void dwt_kernel(const float* __restrict__ src, int cs, int h, int w,
                           int h2, int w2, float* __restrict__ sub)
{
    int t = blockIdx.x * blockDim.x + threadIdx.x;
    int total = Bc * 32 * h2 * w2;
    if (t >= total) return;
    int xx = t % w2; int r = t / w2;
    int yy = r % h2; r /= h2;
    int c = r & 31; int b = r >> 5;
    const float* sp = src + (size_t)cs * (b * 32 + c) * h * w;
    int y0 = yy * 2, x0 = xx * 2;
    bool xe = (x0 + 1 < w), ye = (y0 + 1 < h);
    float a  = sp[y0 * w + x0];
    float bb = xe ? sp[y0 * w + x0 + 1] : 0.f;
    float cc = ye ? sp[(y0 + 1) * w + x0] : 0.f;
    float dd = (xe && ye) ? sp[(y0 + 1) * w + x0 + 1] : 0.f;
    size_t pl = (size_t)h2 * w2;
    size_t ob = (size_t)(b * 128 + c * 4) * pl + yy * w2 + xx;
    sub[ob]          = ( a + bb + cc + dd) * 0.5f;
    sub[ob + pl]     = (-a - bb + cc + dd) * 0.5f;
    sub[ob + 2 * pl] = (-a + bb - cc + dd) * 0.5f;
    sub[ob + 3 * pl] = ( a - bb - cc + dd) * 0.5f;
}

// ---------------- FUSED DWT levels 2-4: one block per (b,c) plane; LL cascades
// through LDS. Bit-identical to three dwt_kernel launches.
__global__ __launch_bounds__(256) void dwt234_kernel(const float* __restrict__ S1,
        float* __restrict__ S2, float* __restrict__ S3, float* __restrict__ S4)
{
    __shared__ float ll[196];
    int bc = blockIdx.x; int b = bc >> 5, c = bc & 31;
    int t = threadIdx.x;
    const float* src = S1 + (size_t)(b * 128 + c * 4) * 196;   // LL plane of S1 (14x14)
    if (t < 196) ll[t] = src[t];
    __syncthreads();
    // level 2: 14x14 -> 7x7
    float l2 = 0.f;
    if (t < 49) {
        int yy = t / 7, xx = t % 7;
        int y0 = yy * 2, x0 = xx * 2;
        float a = ll[y0 * 14 + x0],       bb = ll[y0 * 14 + x0 + 1];
        float cc = ll[(y0 + 1) * 14 + x0], dd = ll[(y0 + 1) * 14 + x0 + 1];
        size_t ob = (size_t)(b * 128 + c * 4) * 49 + t;
        float vll = (a + bb + cc + dd) * 0.5f;
        S2[ob]       = vll;
        S2[ob + 49]  = (-a - bb + cc + dd) * 0.5f;
        S2[ob + 98]  = (-a + bb - cc + dd) * 0.5f;
        S2[ob + 147] = ( a - bb - cc + dd) * 0.5f;
        l2 = vll;
    }
    __syncthreads();
    if (t < 49) ll[t] = l2;
    __syncthreads();
    // level 3: 7x7 (odd, zero-pad) -> 4x4
    float l3 = 0.f;
    if (t < 16) {
        int yy = t >> 2, xx = t & 3;
        int y0 = yy * 2, x0 = xx * 2;
        bool xe = (x0 + 1 < 7), ye = (y0 + 1 < 7);
        float a  = ll[y0 * 7 + x0];
        float bb = xe ? ll[y0 * 7 + x0 + 1] : 0.f;
        float cc = ye ? ll[(y0 + 1) * 7 + x0] : 0.f;
        float dd = (xe && ye) ? ll[(y0 + 1) * 7 + x0 + 1] : 0.f;
        size_t ob = (size_t)(b * 128 + c * 4) * 16 + t;
        float vll = (a + bb + cc + dd) * 0.5f;
        S3[ob]      = vll;
        S3[ob + 16] = (-a - bb + cc + dd) * 0.5f;
        S3[ob + 32] = (-a + bb - cc + dd) * 0.5f;
        S3[ob + 48] = ( a - bb - cc + dd) * 0.5f;
        l3 = vll;
    }
    __syncthreads();
    if (t < 16) ll[t] = l3;
    __syncthreads();
    // level 4: 4x4 -> 2x2
    if (t < 4) {
        int yy = t >> 1, xx = t & 1;
        int y0 = yy * 2, x0 = xx * 2;
        float a = ll[y0 * 4 + x0],       bb = ll[y0 * 4 + x0 + 1];
        float cc = ll[(y0 + 1) * 4 + x0], dd = ll[(y0 + 1) * 4 + x0 + 1];
        size_t ob = (size_t)(b * 128 + c * 4) * 4 + t;
        S4[ob]      = ( a + bb + cc + dd) * 0.5f;
        S4[ob + 4]  = (-a - bb + cc + dd) * 0.5f;
        S4[ob + 8]  = (-a + bb - cc + dd) * 0.5f;
        S4[ob + 12] = ( a - bb - cc + dd) * 0.5f;
    }
}

// ---------------- merged wavelet depthwise 3x3 (all 5 levels, one launch)
template<int H>
__device__ __forceinline__ void dw3_body(int r, const float* __restrict__ src,
        const float* __restrict__ wt, const float* __restrict__ scale,
        float* __restrict__ dst)
{
    int x = r % H; int rr = r / H;
    int y = rr % H; rr /= H;
    int c = rr & 127;
    const float* sp = src + (r - x - y * H);
    float acc = 0.f;
    #pragma unroll
    for (int u = 0; u < 3; u++) {
        int yy = y + u - 1;
        if (yy < 0 || yy >= H) continue;
        #pragma unroll
        for (int v = 0; v < 3; v++) {
            int xx = x + v - 1;
            if (xx < 0 || xx >= H) continue;
            acc += sp[yy * H + xx] * wt[(u * 3 + v) * 128 + c];
        }
    }
    dst[r] = acc * scale[c];
}

__global__ void dw3x3_all_kernel(const float* __restrict__ sub, const float* __restrict__ wavw,
        const float* __restrict__ wavs, float* __restrict__ tt)
{
    int t = blockIdx.x * blockDim.x + threadIdx.x;
    if (t < 3211264)      dw3_body<28>(t,           sub,           wavw,        wavs,       tt);
    else if (t < 4014080) dw3_body<14>(t - 3211264, sub + 3211264, wavw + 1152, wavs + 128, tt + 3211264);
    else if (t < 4214784) dw3_body<7> (t - 4014080, sub + 4014080, wavw + 2304, wavs + 256, tt + 4014080);
    else if (t < 4280320) dw3_body<4> (t - 4214784, sub + 4214784, wavw + 3456, wavs + 384, tt + 4214784);
    else if (t < 4296704) dw3_body<2> (t - 4280320, sub + 4280320, wavw + 4608, wavs + 512, tt + 4280320);
}

// ---------------- FUSED IDWT levels 4..2: one block per (b,c); recon cascades
// through LDS; writes the 14x14 recon (RA equivalent) for level-1 idwt.
__global__ __launch_bounds__(256) void idwt432_kernel(const float* __restrict__ T4,
        const float* __restrict__ T3, const float* __restrict__ T2,
        float* __restrict__ out14)
{
    __shared__ float rec[196];
    int bc = blockIdx.x; int b = bc >> 5, c = bc & 31;
    int t = threadIdx.x;
    // level 4: T4 (2x2 planes) -> 4x4
    float v4 = 0.f;
    if (t < 16) {
        int y = t >> 2, x = t & 3;
        int y2 = y >> 1, x2 = x >> 1;
        size_t base = (size_t)(b * 128 + c * 4) * 4 + y2 * 2 + x2;
        float ll = T4[base];
        float lh = T4[base + 4], hl = T4[base + 8], hh = T4[base + 12];
        float v;
        if ((y & 1) == 0) v = ((x & 1) == 0) ? (ll - lh - hl + hh) : (ll - lh + hl - hh);
        else              v = ((x & 1) == 0) ? (ll + lh - hl - hh) : (ll + lh + hl + hh);
        v4 = v * 0.5f;
    }
    if (t < 16) rec[t] = v4;
    __syncthreads();
    // level 3: T3 (4x4 planes) + rec -> 7x7 (crop from 8x8)
    float v3 = 0.f;
    if (t < 49) {
        int y = t / 7, x = t % 7;
        int y2 = y >> 1, x2 = x >> 1;
        size_t base = (size_t)(b * 128 + c * 4) * 16 + y2 * 4 + x2;
        float ll = T3[base] + rec[y2 * 4 + x2];
        float lh = T3[base + 16], hl = T3[base + 32], hh = T3[base + 48];
        float v;
        if ((y & 1) == 0) v = ((x & 1) == 0) ? (ll - lh - hl + hh) : (ll - lh + hl - hh);
        else              v = ((x & 1) == 0) ? (ll + lh - hl - hh) : (ll + lh + hl + hh);
        v3 = v * 0.5f;
    }
    __syncthreads();
    if (t < 49) rec[t] = v3;
    __syncthreads();
    // level 2: T2 (7x7 planes) + rec -> 14x14, write global
    if (t < 196) {
        int y = t / 14, x = t % 14;
        int y2 = y >> 1, x2 = x >> 1;
        size_t base = (size_t)(b * 128 + c * 4) * 49 + y2 * 7 + x2;
        float ll = T2[base] + rec[y2 * 7 + x2];
        float lh = T2[base + 49], hl = T2[base + 98], hh = T2[base + 147];
        float v;
        if ((y & 1) == 0) v = ((x & 1) == 0) ? (ll - lh - hl + hh) : (ll - lh + hl - hh);
        else              v = ((x & 1) == 0) ? (ll + lh - hl - hh) : (ll + lh + hl + hh);
        out14[(size_t)(b * 32 + c) * 196 + t] = v * 0.5f;
    }
}

// ---------------- Haar IDWT (+ll add, crop) — level 1
__global__ void idwt_kernel(const float* __restrict__ tl, const float* __restrict__ nxt,
        float* __restrict__ outp, int h2, int w2, int ho, int wo)
{
    int t = blockIdx.x * blockDim.x + threadIdx.x;
    int total = Bc * 32 * ho * wo;
    if (t >= total) return;
    int x = t % wo; int r = t / wo;
    int y = r % ho; r /= ho;
    int c = r & 31; int b = r >> 5;
    int y2 = y >> 1, x2 = x >> 1;
    size_t pl = (size_t)h2 * w2;
    size_t base = (size_t)(b * 128 + c * 4) * pl + y2 * w2 + x2;
    float ll = tl[base];
    if (nxt) ll += nxt[(size_t)(b * 32 + c) * pl + y2 * w2 + x2];
    float lh = tl[base + pl], hl = tl[base + 2 * pl], hh = tl[base + 3 * pl];
    float v;
    if ((y & 1) == 0) v = ((x & 1) == 0) ? (ll - lh - hl + hh) : (ll - lh + hl - hh);
    else              v = ((x & 1) == 0) ? (ll + lh - hl - hh) : (ll + lh + hl + hh);
    outp[t] = v * 0.5f;
}

// ---------------- fused idwt level-0 + base depthwise conv -> bf16 NHWC
__global__ void idwt_dwbase_kernel(const float* __restrict__ tl, const float* __restrict__ nxt,
        const float* __restrict__ src, const float* __restrict__ wt,
        const float* __restrict__ scale, const float* __restrict__ bias,
        bf16* __restrict__ dst_nhwc)
{
    int t = blockIdx.x * blockDim.x + threadIdx.x;
    if (t >= Bc * 32 * Nc) return;
    int x = t % Wcc; int r = t / Wcc;
    int y = r % Hc; r /= Hc;
    int c = r & 31; int b = r >> 5;
    int y2 = y >> 1, x2 = x >> 1;
    const size_t pl = 784;
    size_t base = (size_t)(b * 128 + c * 4) * pl + y2 * 28 + x2;
    float ll = tl[base] + nxt[(size_t)(b * 32 + c) * pl + y2 * 28 + x2];
    float lh = tl[base + pl], hl = tl[base + 2 * pl], hh = tl[base + 3 * pl];
    float v;
    if ((y & 1) == 0) v = ((x & 1) == 0) ? (ll - lh - hl + hh) : (ll - lh + hl - hh);
    else              v = ((x & 1) == 0) ? (ll + lh - hl - hh) : (ll + lh + hl + hh);
    float recon = v * 0.5f;
    const float* sp = src + (t - x - y * Wcc);
    float acc = 0.f;
    #pragma unroll
    for (int u = 0; u < 3; u++) {
        int yy = y + u - 1;
        if (yy < 0 || yy >= Hc) continue;
        #pragma unroll
        for (int vv2 = 0; vv2 < 3; vv2++) {
            int xx = x + vv2 - 1;
            if (xx < 0 || xx >= Wcc) continue;
            acc += sp[yy * Wcc + xx] * wt[(u * 3 + vv2) * 32 + c];
        }
    }
    acc = (acc + bias[c]) * scale[c] + recon;
    dst_nhwc[(((size_t)b * Hc + y) * Wcc + x) * 32 + c] = __float2bfloat16(acc);
}

// ---------------- merged weight prep (plain transposes)
__global__ void wprep_kernel(const float* __restrict__ qw, const float* __restrict__ kv1w,
        const float* __restrict__ kv2w, const float* __restrict__ pw,
        const float* __restrict__ f1w, const float* __restrict__ f2w,
        const float* __restrict__ cpw, bf16* __restrict__ qwt, bf16* __restrict__ kv1wt,
        bf16* __restrict__ kv2wt, bf16* __restrict__ pwt, bf16* __restrict__ w1t,
        bf16* __restrict__ w2t, bf16* __restrict__ cpwt)
{
    int t = blockIdx.x * blockDim.x + threadIdx.x;
    if (t < 9216) {
        int n = t % 96, k = t / 96;
        qwt[n * 96 + k] = __float2bfloat16(qw[t]);
    } else if (t < 18432) {
        int u = t - 9216; int n = u % 96, k = u / 96;
        kv1wt[n * 96 + k] = __float2bfloat16(kv1w[u]);
    } else if (t < 27648) {
        int u = t - 18432; int n = u % 96, k = u / 96;
        kv2wt[n * 96 + k] = __float2bfloat16(kv2w[u]);
    } else if (t < 44032) {
        int u = t - 27648; int n = u % 128, k = u / 128;
        pwt[n * 128 + k] = __float2bfloat16(pw[u]);
    } else if (t < 109568) {
        int u = t - 44032; int n = u % 512, k = u / 512;
        w1t[(size_t)n * 128 + k] = __float2bfloat16(f1w[u]);
    } else if (t < 175104) {
        int u = t - 109568; int n = u % 128, k = u / 128;
        w2t[(size_t)n * 512 + k] = __float2bfloat16(f2w[u]);
    } else if (t < 184320) {
        int u = t - 175104; int co = u / 288, k = u % 288;
        cpwt[u] = __float2bfloat16(cpw[k * 32 + co]);
    }
}

// ---------------- cp2d implicit-GEMM MFMA + FUSED cn (LN over 32 ch + gelu)
__global__ __launch_bounds__(256) void cp2d_cn_kernel(const bf16* __restrict__ src,
        const bf16* __restrict__ wtc, const float* __restrict__ bias,
        const float* __restrict__ cnw, const float* __restrict__ cnb,
        bf16* __restrict__ attn_cat)
{
    __shared__ unsigned short in_s[10 * 400];
    __shared__ unsigned short w_s[32 * 296];
    int tid = threadIdx.x;
    int b = blockIdx.y;
    int ty = blockIdx.x / 7, tx = blockIdx.x % 7;
    for (int idx = tid; idx < 1152; idx += 256) {
        int co = idx / 36, j8 = (idx % 36) * 8;
        *(int4*)&w_s[co * 296 + j8] = *(const int4*)(wtc + co * 288 + j8);
    }
    {
        int idx = tid;
        if (idx < 200) {
            int cell = idx >> 1, half = idx & 1;
            int dy = cell / 10, dx = cell % 10;
            int gy = ty * 8 - 1 + dy, gx = tx * 8 - 1 + dx;
            int4 v0 = make_int4(0, 0, 0, 0), v1 = v0;
            if (gy >= 0 && gy < 56 && gx >= 0 && gx < 56) {
                const int4* gp = (const int4*)(src + ((((size_t)b * 56 + gy) * 56 + gx) * 32 + half * 16));
                v0 = gp[0]; v1 = gp[1];
            }
            *(int4*)&in_s[dy * 400 + dx * 40 + half * 16] = v0;
            *(int4*)&in_s[dy * 400 + dx * 40 + half * 16 + 8] = v1;
        }
    }
    __syncthreads();
    int wave = tid >> 6, lane = tid & 63;
    int ml = lane & 15, qd = lane >> 4;
    int m = wave * 16 + ml;
    int ly = m >> 3, lx = m & 7;
    f32x4 acc0 = {0.f, 0.f, 0.f, 0.f}, acc1 = {0.f, 0.f, 0.f, 0.f};
    #pragma unroll
    for (int u = 0; u < 3; u++)
    #pragma unroll
    for (int v = 0; v < 3; v++) {
        bf16x8 af = *(const bf16x8*)&in_s[(ly + u) * 400 + (lx + v) * 40 + qd * 8];
        int k = (u * 3 + v) * 32 + qd * 8;
        bf16x8 b0 = *(const bf16x8*)&w_s[ml * 296 + k];
        bf16x8 b1 = *(const bf16x8*)&w_s[(16 + ml) * 296 + k];
        acc0 = __builtin_amdgcn_mfma_f32_16x16x32_bf16(af, b0, acc0, 0, 0, 0);
        acc1 = __builtin_amdgcn_mfma_f32_16x16x32_bf16(af, b1, acc1, 0, 0, 0);
    }
    float bia0 = bias[ml], bia1 = bias[16 + ml];
    float g0 = cnw[ml], g1 = cnw[16 + ml];
    float be0 = cnb[ml], be1 = cnb[16 + ml];
    #pragma unroll
    for (int r = 0; r < 4; r++) {
        float c0 = acc0[r] + bia0;
        float c1 = acc1[r] + bia1;
        float s = c0 + c1, q = c0 * c0 + c1 * c1;
        #pragma unroll
        for (int o = 8; o; o >>= 1) { s += __shfl_xor(s, o); q += __shfl_xor(q, o); }
        float mean = s * (1.f / 32.f);
        float inv = rsqrtf(q * (1.f / 32.f) - mean * mean + EPSc);
        int mr = wave * 16 + qd * 4 + r;
        int ry = ty * 8 + (mr >> 3), rx = tx * 8 + (mr & 7);
        bf16* op = attn_cat + ((size_t)b * Nc + ry * 56 + rx) * 128 + 96;
        op[ml]      = __float2bfloat16(gelu_f((c0 - mean) * inv * g0 + be0));
        op[16 + ml] = __float2bfloat16(gelu_f((c1 - mean) * inv * g1 + be1));
    }
}

// ---------------- merged sr: both depthwise reductions in one launch
template<int KS, int LD>
__device__ __forceinline__ void sr_body(int t, const float* __restrict__ xa,
        const float* __restrict__ wt, const float* __restrict__ bias,
        float* __restrict__ outp)
{
    int c = t % Cac; int r = t / Cac;
    int j = r % LD; r /= LD;
    int i = r % LD; int b = r / LD;
    float acc = bias[c];
    for (int u = 0; u < KS; u++)
        for (int v = 0; v < KS; v++)
            acc += xa[(size_t)(b * Nc + (i * KS + u) * Wcc + (j * KS + v)) * Cac + c]
                 * wt[(u * KS + v) * Cac + c];
    outp[t] = acc;
}

__global__ void sr_all_kernel(const float* __restrict__ xa,
        const float* __restrict__ sr1w, const float* __restrict__ sr1b, float* __restrict__ x1p,
        const float* __restrict__ sr2w, const float* __restrict__ sr2b, float* __restrict__ x2p)
{
    int t = blockIdx.x * blockDim.x + threadIdx.x;
    if (t < 150528) sr_body<8, 7>(t, xa, sr1w, sr1b, x1p);
    else {
        int u = t - 150528;
        if (u < 602112) sr_body<4, 14>(u, xa, sr2w, sr2b, x2p);
    }
}

// ---------------- merged LN over 96 + gelu -> bf16 (both branches, one launch)
__global__ __launch_bounds__(256) void ln96_all_kernel(
        const float* __restrict__ s1, const float* __restrict__ g1,
        const float* __restrict__ b1, bf16* __restrict__ d1,
        const float* __restrict__ s2, const float* __restrict__ g2,
        const float* __restrict__ b2, bf16* __restrict__ d2)
{
    int wv = threadIdx.x >> 6, lane = threadIdx.x & 63;
    int row = blockIdx.x * 4 + wv;
    const float* sp; const float* g; const float* be; bf16* dst; int r;
    if (row < 1568)      { sp = s1; g = g1; be = b1; dst = d1; r = row; }
    else if (row < 7840) { sp = s2; g = g2; be = b2; dst = d2; r = row - 1568; }
    else return;
    sp += (size_t)r * 96;
    float x0 = sp[lane];
    float x1 = (lane < 32) ? sp[64 + lane] : 0.f;
    float s = x0 + x1, q = x0 * x0 + x1 * x1;
    for (int o = 32; o; o >>= 1) { s += __shfl_xor(s, o); q += __shfl_xor(q, o); }
    float mean = s * (1.f / 96.f);
    float inv = rsqrtf(q * (1.f / 96.f) - mean * mean + EPSc);
    dst[(size_t)r * 96 + lane] =
        __float2bfloat16(gelu_f((x0 - mean) * inv * g[lane] + be[lane]));
    if (lane < 32)
        dst[(size_t)r * 96 + 64 + lane] =
            __float2bfloat16(gelu_f((x1 - mean) * inv * g[64 + lane] + be[64 + lane]));
}

// ---------------- GEMM body (MR=1, NF=6, BK=32), shared by the merged q/kv kernel.
// OMODE: 0 = fp32 row-major, 2 = fp32 head-major Q layout (B,8,N,12)
template<int OMODE>
__device__ __forceinline__ void qkv_body(const bf16* __restrict__ A,
        const bf16* __restrict__ Wt, void* __restrict__ outp,
        int M, int m0, unsigned short (*As)[40], unsigned short (*Bs)[40], int tid)
{
    const int K = 96, Nt = 96;
    int wave = tid >> 6, lane = tid & 63;
    f32x4 acc[6];
    #pragma unroll
    for (int f = 0; f < 6; f++) acc[f] = (f32x4){0.f, 0.f, 0.f, 0.f};
    int ar = tid >> 2, ac = (tid & 3) << 3;
    int ml = wave * 16 + (lane & 15);
    int qd = lane >> 4;
    for (int k0 = 0; k0 < K; k0 += 32) {
        int4 av = make_int4(0, 0, 0, 0);
        if (m0 + ar < M) av = *(const int4*)(A + (size_t)(m0 + ar) * K + k0 + ac);
        *(int4*)&As[ar][ac] = av;
        for (int idx = tid; idx < 384; idx += 256) {
            int br = idx >> 2, bc = (idx & 3) << 3;
            *(int4*)&Bs[br][bc] = *(const int4*)(Wt + (size_t)br * K + k0 + bc);
        }
        __syncthreads();
        bf16x8 af = *(const bf16x8*)&As[ml][qd * 8];
        #pragma unroll
        for (int f = 0; f < 6; f++) {
            bf16x8 bfv = *(const bf16x8*)&Bs[f * 16 + (lane & 15)][qd * 8];
            acc[f] = __builtin_amdgcn_mfma_f32_16x16x32_bf16(af, bfv, acc[f], 0, 0, 0);
        }
        __syncthreads();
    }
    #pragma unroll
    for (int f = 0; f < 6; f++) {
        int n = f * 16 + (lane & 15);
        #pragma unroll
        for (int r = 0; r < 4; r++) {
            int m = m0 + wave * 16 + qd * 4 + r;
            if (m >= M) continue;
            float v = acc[f][r];
            if (OMODE == 2) {
                int b = m / Nc, nn = m - b * Nc;
                int h = n / 12, d = n - h * 12;
                ((float*)outp)[(((size_t)(b * 8 + h)) * Nc + nn) * 12 + d] = v;
            } else
                ((float*)outp)[(size_t)m * Nt + n] = v;
        }
    }
}

// ---------------- merged q + kv1 + kv2 GEMMs (one launch, 1691 blocks)
__global__ __launch_bounds__(256) void qkv_kernel(
        const bf16* __restrict__ XAb,  const bf16* __restrict__ qwt,   float* __restrict__ QB,
        const bf16* __restrict__ X1Bb, const bf16* __restrict__ kv1wt, float* __restrict__ KV1,
        const bf16* __restrict__ X2Bb, const bf16* __restrict__ kv2wt, float* __restrict__ KV2)
{
    __shared__ unsigned short As[64][40];
    __shared__ unsigned short Bs[96][40];
    int by = blockIdx.x;
    int tid = threadIdx.x;
    if (by < 1568)      qkv_body<2>(XAb,  qwt,   QB,  100352, by * 64,          As, Bs, tid);
    else if (by < 1593) qkv_body<0>(X1Bb, kv1wt, KV1, 1568,   (by - 1568) * 64, As, Bs, tid);
    else                qkv_body<0>(X2Bb, kv2wt, KV2, 6272,   (by - 1593) * 64, As, Bs, tid);
}

// ---------------- MFMA GEMM (MR=1, templated K-depth BK). OMODE: 0 = fp32
// row-major, 1 = bf16 row-major
template<int NF, int BK, bool GELU, bool RES, int OMODE>
__global__ __launch_bounds__(256) void gemm_kernel(const bf16* __restrict__ A,
        const bf16* __restrict__ Wt, const float* __restrict__ bias,
        const float* __restrict__ res, void* __restrict__ outp,
        int M, int K, int Nt)
{
    constexpr int TN = 16 * NF;
    __shared__ unsigned short As[64][BK + 8];
    __shared__ unsigned short Bs[TN][BK + 8];
    int tid = threadIdx.x;
    int wave = tid >> 6, lane = tid & 63;
    int m0 = blockIdx.y * 64, n0 = blockIdx.x * TN;
    f32x4 acc[NF];
    #pragma unroll
    for (int f = 0; f < NF; f++) acc[f] = (f32x4){0.f, 0.f, 0.f, 0.f};

    int ar = tid >> 2, ac = (tid & 3) << 3;
    int ml = wave * 16 + (lane & 15);
    int qd = lane >> 4;

    for (int k0 = 0; k0 < K; k0 += BK) {
        #pragma unroll
        for (int i = 0; i < BK / 32; i++) {
            int cc = ac + i * 32;
            int4 av = make_int4(0, 0, 0, 0);
            if (m0 + ar < M) av = *(const int4*)(A + (size_t)(m0 + ar) * K + k0 + cc);
            *(int4*)&As[ar][cc] = av;
        }
        for (int idx = tid; idx < TN * (BK / 8); idx += 256) {
            int br = idx / (BK / 8), bc = (idx % (BK / 8)) * 8;
            *(int4*)&Bs[br][bc] = *(const int4*)(Wt + (size_t)(n0 + br) * K + k0 + bc);
        }
        __syncthreads();
        #pragma unroll
        for (int kk = 0; kk < BK / 32; kk++) {
            bf16x8 af = *(const bf16x8*)&As[ml][kk * 32 + qd * 8];
            #pragma unroll
            for (int f = 0; f < NF; f++) {
                bf16x8 bfv = *(const bf16x8*)&Bs[f * 16 + (lane & 15)][kk * 32 + qd * 8];
                acc[f] = __builtin_amdgcn_mfma_f32_16x16x32_bf16(af, bfv, acc[f], 0, 0, 0);
            }
        }
        __syncthreads();
    }
    #pragma unroll
    for (int f = 0; f < NF; f++) {
        int n = n0 + f * 16 + (lane & 15);
        #pragma unroll
        for (int r = 0; r < 4; r++) {
            int m = m0 + wave * 16 + qd * 4 + r;
            if (m >= M) continue;
            float v = acc[f][r];
            if (bias) v += bias[n];
            if (GELU) v = gelu_f(v);
            if (RES)  v += res[(size_t)m * Nt + n];
            if (OMODE == 1)
                ((bf16*)outp)[(size_t)m * Nt + n] = __float2bfloat16(v);
            else
                ((float*)outp)[(size_t)m * Nt + n] = v;
        }
    }
}

// ---------------- proj GEMM (K=128, TN=128 full rows) + bias + residual + FUSED LN2.
__global__ __launch_bounds__(256) void proj_ln_kernel(const bf16* __restrict__ A,
        const bf16* __restrict__ Wt, const float* __restrict__ bias,
        const float* __restrict__ res, const float* __restrict__ g,
        const float* __restrict__ be, float* __restrict__ xres, bf16* __restrict__ xnb)
{
    __shared__ unsigned short As[64][72];
    __shared__ unsigned short Bs[128][72];
    int tid = threadIdx.x;
    int wave = tid >> 6, lane = tid & 63;
    int m0 = blockIdx.x * 64;
    f32x4 acc[8];
    #pragma unroll
    for (int f = 0; f < 8; f++) acc[f] = (f32x4){0.f, 0.f, 0.f, 0.f};

    int ar = tid >> 2, ac = (tid & 3) << 3;
    int ml = lane & 15, qd = lane >> 4;
    int mlw = wave * 16 + ml;

    for (int k0 = 0; k0 < 128; k0 += 64) {
        #pragma unroll
        for (int i = 0; i < 2; i++) {
            int cc = ac + i * 32;
            *(int4*)&As[ar][cc] = *(const int4*)(A + (size_t)(m0 + ar) * 128 + k0 + cc);
        }
        for (int idx = tid; idx < 1024; idx += 256) {
            int br = idx >> 3, bc = (idx & 7) * 8;
            *(int4*)&Bs[br][bc] = *(const int4*)(Wt + (size_t)br * 128 + k0 + bc);
        }
        __syncthreads();
        #pragma unroll
        for (int kk = 0; kk < 2; kk++) {
            bf16x8 af = *(const bf16x8*)&As[mlw][kk * 32 + qd * 8];
            #pragma unroll
            for (int f = 0; f < 8; f++) {
                bf16x8 bfv = *(const bf16x8*)&Bs[f * 16 + ml][kk * 32 + qd * 8];
                acc[f] = __builtin_amdgcn_mfma_f32_16x16x32_bf16(af, bfv, acc[f], 0, 0, 0);
            }
        }
        __syncthreads();
    }
    float bia[8], gg[8], bb[8];
    #pragma unroll
    for (int f = 0; f < 8; f++) {
        int n = f * 16 + ml;
        bia[f] = bias[n]; gg[f] = g[n]; bb[f] = be[n];
    }
    #pragma unroll
    for (int r = 0; r < 4; r++) {
        int m = m0 + wave * 16 + qd * 4 + r;
        float vv[8];
        float s = 0.f, q = 0.f;
        #pragma unroll
        for (int f = 0; f < 8; f++) {
            int n = f * 16 + ml;
            float v = acc[f][r] + bia[f] + res[(size_t)m * 128 + n];
            vv[f] = v; s += v; q += v * v;
        }
        #pragma unroll
        for (int o = 8; o; o >>= 1) { s += __shfl_xor(s, o); q += __shfl_xor(q, o); }
        float mean = s * (1.f / 128.f);
        float inv = rsqrtf(q * (1.f / 128.f) - mean * mean + EPSc);
        #pragma unroll
        for (int f = 0; f < 8; f++) {
            int n = f * 16 + ml;
            xres[(size_t)m * 128 + n] = vv[f];
            xnb[(size_t)m * 128 + n] =
                __float2bfloat16((vv[f] - mean) * inv * gg[f] + bb[f]);
        }
    }
}

// ---------------- attention body: round-1 proven shape + raw v_exp_f32 (125us):
// fp32 K/V in LDS, 1 query/thread, branchless single-pass softmax.
template<int L>
__device__ __forceinline__ void attn_body(const float* __restrict__ qh,
        const float* __restrict__ kv, int hl, int h, int b,
        float* kb, float* vb, bf16* __restrict__ attn_cat)
{
    for (int idx = threadIdx.x; idx < L * 3; idx += 256) {
        int l = idx / 3, f = idx % 3;
        const float4* kp = (const float4*)(kv + (size_t)(b * L + l) * 96 + hl * 12) + f;
        float4 kk = kp[0];
        float4 vv = kp[12];
        *(float4*)&kb[l * 12 + f * 4] = kk;
        *(float4*)&vb[l * 12 + f * 4] = vv;
    }
    int n = blockIdx.x * 256 + threadIdx.x;
    bool act = (n < Nc);
    int nn = act ? n : (Nc - 1);
    const float4* qp = (const float4*)(qh + (((size_t)(b * 8 + h)) * Nc + nn) * 12);
    float4 q0 = qp[0], q1 = qp[1], q2 = qp[2];
    const float PRE = SCALEc * 1.4426950408889634f;   /* scale * log2(e) */
    q0.x *= PRE; q0.y *= PRE; q0.z *= PRE; q0.w *= PRE;
    q1.x *= PRE; q1.y *= PRE; q1.z *= PRE; q1.w *= PRE;
    q2.x *= PRE; q2.y *= PRE; q2.z *= PRE; q2.w *= PRE;
    __syncthreads();

    float den = 0.f;
    float o[12];
    #pragma unroll
    for (int d = 0; d < 12; d++) o[d] = 0.f;

    #pragma unroll 4
    for (int l = 0; l < L; l++) {
        const float4 k0 = *(const float4*)&kb[l * 12];
        const float4 k1 = *(const float4*)&kb[l * 12 + 4];
        const float4 k2 = *(const float4*)&kb[l * 12 + 8];
        float s0 = q0.x * k0.x + q0.y * k0.y + q0.z * k0.z + q0.w * k0.w;
        float s1 = q1.x * k1.x + q1.y * k1.y + q1.z * k1.z + q1.w * k1.w;
        float s2 = q2.x * k2.x + q2.y * k2.y + q2.z * k2.z + q2.w * k2.w;
        float e = fast_exp2(s0 + s1 + s2);
        den += e;
        const float4 v0 = *(const float4*)&vb[l * 12];
        const float4 v1 = *(const float4*)&vb[l * 12 + 4];
        const float4 v2 = *(const float4*)&vb[l * 12 + 8];
        o[0] += e * v0.x; o[1]  += e * v0.y; o[2]  += e * v0.z; o[3]  += e * v0.w;
        o[4] += e * v1.x; o[5]  += e * v1.y; o[6]  += e * v1.z; o[7]  += e * v1.w;
        o[8] += e * v2.x; o[9]  += e * v2.y; o[10] += e * v2.z; o[11] += e * v2.w;
    }
    if (act) {
        float rden = 1.f / den;
        bf16* op = attn_cat + (size_t)(b * Nc + n) * 128 + h * 12;
        #pragma unroll
        for (int d = 0; d < 12; d++) op[d] = __float2bfloat16(o[d] * rden);
    }
}

__global__ __launch_bounds__(256) void attn_kernel(const float* __restrict__ qh,
        const float* __restrict__ kv1, const float* __restrict__ kv2,
        bf16* __restrict__ attn_cat)
{
    __shared__ float kb[196 * 12];
    __shared__ float vb[196 * 12];
    int h = blockIdx.y, b = blockIdx.z;
    if (h < 4) attn_body<49> (qh, kv1, h,     h, b, kb, vb, attn_cat);
    else       attn_body<196>(qh, kv2, h - 4, h, b, kb, vb, attn_cat);
}

extern "C" void kernel_launch(void* const* d_in, const int* in_sizes, int n_in,
                              void* d_out, int out_size, void* d_ws, size_t ws_size,
                              hipStream_t stream)
{
    const float* x    = (const float*)d_in[0];
    const float* ln1w = (const float*)d_in[3];
    const float* ln1b = (const float*)d_in[4];
    const float* ln2w = (const float*)d_in[5];
    const float* ln2b = (const float*)d_in[6];
    const float* qw   = (const float*)d_in[7];
    const float* kv1w = (const float*)d_in[8];
    const float* kv2w = (const float*)d_in[9];
    const float* sr1w = (const float*)d_in[10];
    const float* sr1b = (const float*)d_in[11];
    const float* sr2w = (const float*)d_in[12];
    const float* sr2b = (const float*)d_in[13];
    const float* an1w = (const float*)d_in[14];
    const float* an1b = (const float*)d_in[15];
    const float* an2w = (const float*)d_in[16];
    const float* an2b = (const float*)d_in[17];
    const float* wbw  = (const float*)d_in[18];
    const float* wbb  = (const float*)d_in[19];
    const float* wbs  = (const float*)d_in[20];
    const float* wavw = (const float*)d_in[21];
    const float* wavs = (const float*)d_in[22];
    const float* cpw  = (const float*)d_in[23];
    const float* cpb  = (const float*)d_in[24];
    const float* cnw  = (const float*)d_in[25];
    const float* cnb  = (const float*)d_in[26];
    const float* pw   = (const float*)d_in[27];
    const float* pb   = (const float*)d_in[28];
    const float* f1w  = (const float*)d_in[29];
    const float* f1b  = (const float*)d_in[30];
    const float* f2w  = (const float*)d_in[31];
    const float* f2b  = (const float*)d_in[32];
    float* dout = (float*)d_out;
    float* ws = (float*)d_ws;

    float* XA    = ws;                      // 9,633,792
    float* QB    = ws + 9633792;            // head-major Q (B,8,N,12)
    float* XRES  = ws;                      // overlay
    bf16*  XNb   = (bf16*)(ws + 12845056);
    bf16*  XAb   = (bf16*)(ws + 19267584);
    bf16*  ACATb = (bf16*)(ws + 24084480);
    float* XCI   = ws + 30507008;
    float* SUB   = ws + 33718272;
    float* TT    = ws + 38014976;
    float* RA    = ws + 42311680;
    float* RB    = ws + 45522944;
    float* X1P   = ws + 48734208;
    float* X2P   = ws + 48884736;
    bf16*  X1Bb  = (bf16*)(ws + 49486848);
    bf16*  X2Bb  = (bf16*)(ws + 49562112);
    float* KV1   = ws + 49863168;
    float* KV2   = ws + 50013696;
    bf16*  WTB   = (bf16*)(ws + 50615808);
    bf16*  qwt   = WTB;
    bf16*  kv1wt = WTB + 9216;
    bf16*  kv2wt = WTB + 18432;
    bf16*  pwt   = WTB + 27648;
    bf16*  w1t   = WTB + 44032;
    bf16*  w2t   = WTB + 109568;
    bf16*  cpwt  = WTB + 175104;
    bf16*  Hb    = (bf16*)(ws + 24084480);  // overlays ACATb (dead after proj)
    bf16*  CIMGb = (bf16*)SUB;
    float* S0 = SUB;            float* T0 = TT;
    float* S1 = SUB + 3211264;  float* T1 = TT + 3211264;
    float* S2 = SUB + 4014080;  float* T2 = TT + 4014080;
    float* S3 = SUB + 4214784;  float* T3 = TT + 4214784;
    float* S4 = SUB + 4280320;  float* T4 = TT + 4280320;

    // 0. weight preps (single merged launch)
    wprep_kernel<<<720, 256, 0, stream>>>(qw, kv1w, kv2w, pw, f1w, f2w, cpw,
                                          qwt, kv1wt, kv2wt, pwt, w1t, w2t, cpwt);

    // 1. LN1
    ln1_kernel<<<25088, 256, 0, stream>>>(x, ln1w, ln1b, XA, XAb, XCI);

    // 2. DWT: levels 0,1 elementwise; levels 2-4 fused per-plane
    dwt_kernel<<<3136, 256, 0, stream>>>(XCI, 1, 56, 56, 28, 28, S0);
    dwt_kernel<<<784,  256, 0, stream>>>(S0, 4, 28, 28, 14, 14, S1);
    dwt234_kernel<<<1024, 256, 0, stream>>>(S1, S2, S3, S4);

    // 3. ALL wavelet depthwise convs in one launch
    dw3x3_all_kernel<<<16784, 256, 0, stream>>>(SUB, wavw, wavs, TT);

    // 4. IDWT: levels 4-2 fused (writes 14x14 recon into RA); level 1 separate
    idwt432_kernel<<<1024, 256, 0, stream>>>(T4, T3, T2, RA);
    idwt_kernel<<<3136, 256, 0, stream>>>(T1, RA, RB, 14, 14, 28, 28);

    // 5. fused idwt level-0 + base depthwise conv -> bf16 NHWC
    idwt_dwbase_kernel<<<12544, 256, 0, stream>>>(T0, RB, XCI, wbw, wbs, wbb, CIMGb);

    // 6. cp2d implicit-GEMM MFMA + fused cn -> ACATb[96:128]
    cp2d_cn_kernel<<<dim3(49, 32), 256, 0, stream>>>(CIMGb, cpwt, cpb, cnw, cnb, ACATb);

    // 7. merged spatial reductions
    sr_all_kernel<<<2940, 256, 0, stream>>>(XA, sr1w, sr1b, X1P, sr2w, sr2b, X2P);

    // 8. merged LN96 + gelu -> bf16
    ln96_all_kernel<<<1960, 256, 0, stream>>>(X1P, an1w, an1b, X1Bb,
                                              X2P, an2w, an2b, X2Bb);

    // 9. merged q + kv1 + kv2 GEMMs (one launch)
    qkv_kernel<<<1691, 256, 0, stream>>>(XAb, qwt, QB, X1Bb, kv1wt, KV1, X2Bb, kv2wt, KV2);

    // 10. merged attention -> ACATb[0:96]
    attn_kernel<<<dim3(13, 8, 32), 256, 0, stream>>>(QB, KV1, KV2, ACATb);

    // 11. proj + bias + residual(x) + FUSED LN2 -> XRES fp32 + XNb bf16
    proj_ln_kernel<<<1568, 256, 0, stream>>>(ACATb, pwt, pb, x, ln2w, ln2b, XRES, XNb);

    // 12. fc1 + bias + gelu -> Hb bf16  (BK=64; round-10 proven)
    gemm_kernel<4,64,true,false,1><<<dim3(8, 1568), 256, 0, stream>>>(XNb, w1t, f1b, nullptr, Hb, 100352, 128, 512);

    // 13. fc2 + bias + residual(XRES) -> d_out fp32  (round-10 proven shape)
    gemm_kernel<4,64,false,true,0><<<dim3(2, 1568), 256, 0, stream>>>(Hb, w2t, f2b, XRES, dout, 100352, 512, 128);
}

// Round 15
// 570.056 us; speedup vs baseline: 1.0861x; 1.0393x over previous
//
#include <hip/hip_runtime.h>
#include <hip/hip_bf16.h>
#include <math.h>

typedef __hip_bfloat16 bf16;
typedef __attribute__((ext_vector_type(8))) short bf16x8;
typedef __attribute__((ext_vector_type(4))) float f32x4;

#define Bc   32
#define Hc   56
#define Wcc  56
#define Nc   3136
#define Cpc  32
#define Cac  96
#define EPSc 1e-5f
#define SCALEc 0.28867513459481287f   /* 1/sqrt(12) */

__device__ __forceinline__ float gelu_f(float x) {
    return 0.5f * x * (1.0f + erff(x * 0.7071067811865475f));
}

// raw v_exp_f32 (2^x). Fallback keeps correctness if builtin is absent.
__device__ __forceinline__ float fast_exp2(float x) {
#if defined(__has_builtin)
#if __has_builtin(__builtin_amdgcn_exp2f)
    return __builtin_amdgcn_exp2f(x);
#else
    return exp2f(x);
#endif
#else
    return exp2f(x);
#endif
}

// ---------------- LN1: (B,N,128) -> xa fp32 (B,N,96) + xab bf16 + xc_img (B,32,56,56) fp32
__global__ __launch_bounds__(256) void ln1_kernel(const float* __restrict__ x,
        const float* __restrict__ g, const float* __restrict__ be,
        float* __restrict__ xa, bf16* __restrict__ xab, float* __restrict__ xc_img)
{
    int wv = threadIdx.x >> 6, lane = threadIdx.x & 63;
    int row = blockIdx.x * 4 + wv;
    if (row >= Bc * Nc) return;
    const float* xr = x + (size_t)row * 128;
    float x0 = xr[lane];
    float x1 = xr[lane + 64];
    float s = x0 + x1, q = x0 * x0 + x1 * x1;
    for (int o = 32; o; o >>= 1) { s += __shfl_xor(s, o); q += __shfl_xor(q, o); }
    float mean = s * (1.f / 128.f);
    float inv = rsqrtf(q * (1.f / 128.f) - mean * mean + EPSc);
    int b = row / Nc, n = row % Nc;
    {
        int c = lane;
        float y = (x0 - mean) * inv * g[c] + be[c];
        if (c < Cpc) xc_img[(size_t)(b * Cpc + c) * Nc + n] = y;
        else { xa[(size_t)row * Cac + (c - Cpc)] = y;
               xab[(size_t)row * Cac + (c - Cpc)] = __float2bfloat16(y); }
    }
    {
        int c = lane + 64;
        float y = (x1 - mean) * inv * g[c] + be[c];
        xa[(size_t)row * Cac + (c - Cpc)] = y;
        xab[(size_t)row * Cac + (c - Cpc)] = __float2bfloat16(y);
    }
}

// ---------------- FUSED DWT all 5 levels: one block per (b,c) plane; XCI plane
// staged in LDS; LL cascades through ping-pong buffers. Writes S0..S4 at the
// exact offsets the separate kernels used. Bit-identical math.
__global__ __launch_bounds__(256) void dwt_all_kernel(const float* __restrict__ xci,
        float* __restrict__ S0, float* __restrict__ S1, float* __restrict__ S2,
        float* __restrict__ S3, float* __restrict__ S4)
{
    __shared__ float bufA[3136];
    __shared__ float bufB[784];
    int bc = blockIdx.x; int b = bc >> 5, c = bc & 31;
    int t = threadIdx.x;
    const float* src = xci + (size_t)(b * 32 + c) * 3136;
    for (int i = t; i < 3136; i += 256) bufA[i] = src[i];
    __syncthreads();
    // level 0: 56x56 -> 28x28 (even dims, no pad)
    for (int p = t; p < 784; p += 256) {
        int yy = p / 28, xx = p % 28;
        int y0 = yy * 2, x0 = xx * 2;
        float a = bufA[y0 * 56 + x0],        bb = bufA[y0 * 56 + x0 + 1];
        float cc = bufA[(y0 + 1) * 56 + x0], dd = bufA[(y0 + 1) * 56 + x0 + 1];
        size_t ob = (size_t)(b * 128 + c * 4) * 784 + p;
        float vll = (a + bb + cc + dd) * 0.5f;
        S0[ob]         = vll;
        S0[ob + 784]   = (-a - bb + cc + dd) * 0.5f;
        S0[ob + 1568]  = (-a + bb - cc + dd) * 0.5f;
        S0[ob + 2352]  = ( a - bb - cc + dd) * 0.5f;
        bufB[p] = vll;
    }
    __syncthreads();
    // level 1: 28x28 -> 14x14
    for (int p = t; p < 196; p += 256) {
        int yy = p / 14, xx = p % 14;
        int y0 = yy * 2, x0 = xx * 2;
        float a = bufB[y0 * 28 + x0],        bb = bufB[y0 * 28 + x0 + 1];
        float cc = bufB[(y0 + 1) * 28 + x0], dd = bufB[(y0 + 1) * 28 + x0 + 1];
        size_t ob = (size_t)(b * 128 + c * 4) * 196 + p;
        float vll = (a + bb + cc + dd) * 0.5f;
        S1[ob]       = vll;
        S1[ob + 196] = (-a - bb + cc + dd) * 0.5f;
        S1[ob + 392] = (-a + bb - cc + dd) * 0.5f;
        S1[ob + 588] = ( a - bb - cc + dd) * 0.5f;
        bufA[p] = vll;
    }
    __syncthreads();
    // level 2: 14x14 -> 7x7
    if (t < 49) {
        int yy = t / 7, xx = t % 7;
        int y0 = yy * 2, x0 = xx * 2;
        float a = bufA[y0 * 14 + x0],        bb = bufA[y0 * 14 + x0 + 1];
        float cc = bufA[(y0 + 1) * 14 + x0], dd = bufA[(y0 + 1) * 14 + x0 + 1];
        size_t ob = (size_t)(b * 128 + c * 4) * 49 + t;
        float vll = (a + bb + cc + dd) * 0.5f;
        S2[ob]       = vll;
        S2[ob + 49]  = (-a - bb + cc + dd) * 0.5f;
        S2[ob + 98]  = (-a + bb - cc + dd) * 0.5f;
        S2[ob + 147] = ( a - bb - cc + dd) * 0.5f;
        bufB[t] = vll;
    }
    __syncthreads();
    // level 3: 7x7 (odd, zero-pad) -> 4x4
    if (t < 16) {
        int yy = t >> 2, xx = t & 3;
        int y0 = yy * 2, x0 = xx * 2;
        bool xe = (x0 + 1 < 7), ye = (y0 + 1 < 7);
        float a  = bufB[y0 * 7 + x0];
        float bb = xe ? bufB[y0 * 7 + x0 + 1] : 0.f;
        float cc = ye ? bufB[(y0 + 1) * 7 + x0] : 0.f;
        float dd = (xe && ye) ? bufB[(y0 + 1) * 7 + x0 + 1] : 0.f;
        size_t ob = (size_t)(b * 128 + c * 4) * 16 + t;
        float vll = (a + bb + cc + dd) * 0.5f;
        S3[ob]      = vll;
        S3[ob + 16] = (-a - bb + cc + dd) * 0.5f;
        S3[ob + 32] = (-a + bb - cc + dd) * 0.5f;
        S3[ob + 48] = ( a - bb - cc + dd) * 0.5f;
        bufA[t] = vll;
    }
    __syncthreads();
    // level 4: 4x4 -> 2x2
    if (t < 4) {
        int yy = t >> 1, xx = t & 1;
        int y0 = yy * 2, x0 = xx * 2;
        float a = bufA[y0 * 4 + x0],        bb = bufA[y0 * 4 + x0 + 1];
        float cc = bufA[(y0 + 1) * 4 + x0], dd = bufA[(y0 + 1) * 4 + x0 + 1];
        size_t ob = (size_t)(b * 128 + c * 4) * 4 + t;
        S4[ob]      = ( a + bb + cc + dd) * 0.5f;
        S4[ob + 4]  = (-a - bb + cc + dd) * 0.5f;
        S4[ob + 8]  = (-a + bb - cc + dd) * 0.5f;
        S4[ob + 12] = ( a - bb - cc + dd) * 0.5f;
    }
}

// ---------------- merged wavelet depthwise 3x3 (all 5 levels, one launch)
template<int H>
__device__ __forceinline__ void dw3_body(int r, const float* __restrict__ src,
        const float* __restrict__ wt, const float* __restrict__ scale,
        float* __restrict__ dst)
{
    int x = r % H; int rr = r / H;
    int y = rr % H; rr /= H;
    int c = rr & 127;
    const float* sp = src + (r - x - y * H);
    float acc = 0.f;
    #pragma unroll
    for (int u = 0; u < 3; u++) {
        int yy = y + u - 1;
        if (yy < 0 || yy >= H) continue;
        #pragma unroll
        for (int v = 0; v < 3; v++) {
            int xx = x + v - 1;
            if (xx < 0 || xx >= H) continue;
            acc += sp[yy * H + xx] * wt[(u * 3 + v) * 128 + c];
        }
    }
    dst[r] = acc * scale[c];
}

__global__ void dw3x3_all_kernel(const float* __restrict__ sub, const float* __restrict__ wavw,
        const float* __restrict__ wavs, float* __restrict__ tt)
{
    int t = blockIdx.x * blockDim.x + threadIdx.x;
    if (t < 3211264)      dw3_body<28>(t,           sub,           wavw,        wavs,       tt);
    else if (t < 4014080) dw3_body<14>(t - 3211264, sub + 3211264, wavw + 1152, wavs + 128, tt + 3211264);
    else if (t < 4214784) dw3_body<7> (t - 4014080, sub + 4014080, wavw + 2304, wavs + 256, tt + 4014080);
    else if (t < 4280320) dw3_body<4> (t - 4214784, sub + 4214784, wavw + 3456, wavs + 384, tt + 4214784);
    else if (t < 4296704) dw3_body<2> (t - 4280320, sub + 4280320, wavw + 4608, wavs + 512, tt + 4280320);
}

// ---------------- FUSED IDWT levels 4..1 + level-0 + base depthwise conv.
// One block per (b,c): recon cascades through LDS ping-pong (2x2->4x4->7x7->
// 14x14->28x28); XCI plane staged in LDS for the 3x3 conv (9x reuse);
// per-pixel level-0 idwt from T0 (global, L2-hot). Bit-identical math to the
// idwt432 + idwt1 + idwt_dwbase chain; kills the RA/RB round-trips.
__global__ __launch_bounds__(256) void idwt_all_dwbase_kernel(
        const float* __restrict__ T4, const float* __restrict__ T3,
        const float* __restrict__ T2, const float* __restrict__ T1,
        const float* __restrict__ T0, const float* __restrict__ xci,
        const float* __restrict__ wt, const float* __restrict__ scale,
        const float* __restrict__ bias, bf16* __restrict__ dst_nhwc)
{
    __shared__ float xs[3136];     // XCI plane
    __shared__ float r28[784];     // recon ping (also holds 7x7 stage)
    __shared__ float rS[196];      // recon pong (4x4, 14x14 stages)
    int bc = blockIdx.x; int b = bc >> 5, c = bc & 31;
    int t = threadIdx.x;
    const float* xsrc = xci + (size_t)(b * 32 + c) * 3136;
    for (int i = t; i < 3136; i += 256) xs[i] = xsrc[i];
    // level 4: T4 (2x2) -> 4x4 into rS[0..16)
    if (t < 16) {
        int y = t >> 2, x = t & 3;
        size_t base = (size_t)(b * 128 + c * 4) * 4 + (y >> 1) * 2 + (x >> 1);
        float ll = T4[base];
        float lh = T4[base + 4], hl = T4[base + 8], hh = T4[base + 12];
        float v;
        if ((y & 1) == 0) v = ((x & 1) == 0) ? (ll - lh - hl + hh) : (ll - lh + hl - hh);
        else              v = ((x & 1) == 0) ? (ll + lh - hl - hh) : (ll + lh + hl + hh);
        rS[t] = v * 0.5f;
    }
    __syncthreads();
    // level 3: T3 (4x4) + rS -> 7x7 into r28[0..49)
    if (t < 49) {
        int y = t / 7, x = t % 7;
        int y2 = y >> 1, x2 = x >> 1;
        size_t base = (size_t)(b * 128 + c * 4) * 16 + y2 * 4 + x2;
        float ll = T3[base] + rS[y2 * 4 + x2];
        float lh = T3[base + 16], hl = T3[base + 32], hh = T3[base + 48];
        float v;
        if ((y & 1) == 0) v = ((x & 1) == 0) ? (ll - lh - hl + hh) : (ll - lh + hl - hh);
        else              v = ((x & 1) == 0) ? (ll + lh - hl - hh) : (ll + lh + hl + hh);
        r28[t] = v * 0.5f;
    }
    __syncthreads();
    // level 2: T2 (7x7) + r28 -> 14x14 into rS[0..196)
    if (t < 196) {
        int y = t / 14, x = t % 14;
        int y2 = y >> 1, x2 = x >> 1;
        size_t base = (size_t)(b * 128 + c * 4) * 49 + y2 * 7 + x2;
        float ll = T2[base] + r28[y2 * 7 + x2];
        float lh = T2[base + 49], hl = T2[base + 98], hh = T2[base + 147];
        float v;
        if ((y & 1) == 0) v = ((x & 1) == 0) ? (ll - lh - hl + hh) : (ll - lh + hl - hh);
        else              v = ((x & 1) == 0) ? (ll + lh - hl - hh) : (ll + lh + hl + hh);
        rS[t] = v * 0.5f;
    }
    __syncthreads();
    // level 1: T1 (14x14) + rS -> 28x28 into r28[0..784)
    for (int p = t; p < 784; p += 256) {
        int y = p / 28, x = p % 28;
        int y2 = y >> 1, x2 = x >> 1;
        size_t base = (size_t)(b * 128 + c * 4) * 196 + y2 * 14 + x2;
        float ll = T1[base] + rS[y2 * 14 + x2];
        float lh = T1[base + 196], hl = T1[base + 392], hh = T1[base + 588];
        float v;
        if ((y & 1) == 0) v = ((x & 1) == 0) ? (ll - lh - hl + hh) : (ll - lh + hl - hh);
        else              v = ((x & 1) == 0) ? (ll + lh - hl - hh) : (ll + lh + hl + hh);
        r28[p] = v * 0.5f;
    }
    __syncthreads();
    // level 0 + base 3x3 depthwise conv, per pixel
    float w9[9];
    #pragma unroll
    for (int i = 0; i < 9; i++) w9[i] = wt[i * 32 + c];
    float bia = bias[c], scl = scale[c];
    for (int p = t; p < 3136; p += 256) {
        int y = p / 56, x = p % 56;
        int y2 = y >> 1, x2 = x >> 1;
        size_t base = (size_t)(b * 128 + c * 4) * 784 + y2 * 28 + x2;
        float ll = T0[base] + r28[y2 * 28 + x2];
        float lh = T0[base + 784], hl = T0[base + 1568], hh = T0[base + 2352];
        float v;
        if ((y & 1) == 0) v = ((x & 1) == 0) ? (ll - lh - hl + hh) : (ll - lh + hl - hh);
        else              v = ((x & 1) == 0) ? (ll + lh - hl - hh) : (ll + lh + hl + hh);
        float recon = v * 0.5f;
        float acc = 0.f;
        #pragma unroll
        for (int u = 0; u < 3; u++) {
            int yy = y + u - 1;
            if (yy < 0 || yy >= 56) continue;
            #pragma unroll
            for (int vv = 0; vv < 3; vv++) {
                int xx = x + vv - 1;
                if (xx < 0 || xx >= 56) continue;
                acc += xs[yy * 56 + xx] * w9[u * 3 + vv];
            }
        }
        acc = (acc + bia) * scl + recon;
        dst_nhwc[(((size_t)b * 56 + y) * 56 + x) * 32 + c] = __float2bfloat16(acc);
    }
}

// ---------------- merged weight prep (plain transposes)
__global__ void wprep_kernel(const float* __restrict__ qw, const float* __restrict__ kv1w,
        const float* __restrict__ kv2w, const float* __restrict__ pw,
        const float* __restrict__ f1w, const float* __restrict__ f2w,
        const float* __restrict__ cpw, bf16* __restrict__ qwt, bf16* __restrict__ kv1wt,
        bf16* __restrict__ kv2wt, bf16* __restrict__ pwt, bf16* __restrict__ w1t,
        bf16* __restrict__ w2t, bf16* __restrict__ cpwt)
{
    int t = blockIdx.x * blockDim.x + threadIdx.x;
    if (t < 9216) {
        int n = t % 96, k = t / 96;
        qwt[n * 96 + k] = __float2bfloat16(qw[t]);
    } else if (t < 18432) {
        int u = t - 9216; int n = u % 96, k = u / 96;
        kv1wt[n * 96 + k] = __float2bfloat16(kv1w[u]);
    } else if (t < 27648) {
        int u = t - 18432; int n = u % 96, k = u / 96;
        kv2wt[n * 96 + k] = __float2bfloat16(kv2w[u]);
    } else if (t < 44032) {
        int u = t - 27648; int n = u % 128, k = u / 128;
        pwt[n * 128 + k] = __float2bfloat16(pw[u]);
    } else if (t < 109568) {
        int u = t - 44032; int n = u % 512, k = u / 512;
        w1t[(size_t)n * 128 + k] = __float2bfloat16(f1w[u]);
    } else if (t < 175104) {
        int u = t - 109568; int n = u % 128, k = u / 128;
        w2t[(size_t)n * 512 + k] = __float2bfloat16(f2w[u]);
    } else if (t < 184320) {
        int u = t - 175104; int co = u / 288, k = u % 288;
        cpwt[u] = __float2bfloat16(cpw[k * 32 + co]);
    }
}

// ---------------- cp2d implicit-GEMM MFMA + FUSED cn (LN over 32 ch + gelu)
__global__ __launch_bounds__(256) void cp2d_cn_kernel(const bf16* __restrict__ src,
        const bf16* __restrict__ wtc, const float* __restrict__ bias,
        const float* __restrict__ cnw, const float* __restrict__ cnb,
        bf16* __restrict__ attn_cat)
{
    __shared__ unsigned short in_s[10 * 400];
    __shared__ unsigned short w_s[32 * 296];
    int tid = threadIdx.x;
    int b = blockIdx.y;
    int ty = blockIdx.x / 7, tx = blockIdx.x % 7;
    for (int idx = tid; idx < 1152; idx += 256) {
        int co = idx / 36, j8 = (idx % 36) * 8;
        *(int4*)&w_s[co * 296 + j8] = *(const int4*)(wtc + co * 288 + j8);
    }
    {
        int idx = tid;
        if (idx < 200) {
            int cell = idx >> 1, half = idx & 1;
            int dy = cell / 10, dx = cell % 10;
            int gy = ty * 8 - 1 + dy, gx = tx * 8 - 1 + dx;
            int4 v0 = make_int4(0, 0, 0, 0), v1 = v0;
            if (gy >= 0 && gy < 56 && gx >= 0 && gx < 56) {
                const int4* gp = (const int4*)(src + ((((size_t)b * 56 + gy) * 56 + gx) * 32 + half * 16));
                v0 = gp[0]; v1 = gp[1];
            }
            *(int4*)&in_s[dy * 400 + dx * 40 + half * 16] = v0;
            *(int4*)&in_s[dy * 400 + dx * 40 + half * 16 + 8] = v1;
        }
    }
    __syncthreads();
    int wave = tid >> 6, lane = tid & 63;
    int ml = lane & 15, qd = lane >> 4;
    int m = wave * 16 + ml;
    int ly = m >> 3, lx = m & 7;
    f32x4 acc0 = {0.f, 0.f, 0.f, 0.f}, acc1 = {0.f, 0.f, 0.f, 0.f};
    #pragma unroll
    for (int u = 0; u < 3; u++)
    #pragma unroll
    for (int v = 0; v < 3; v++) {
        bf16x8 af = *(const bf16x8*)&in_s[(ly + u) * 400 + (lx + v) * 40 + qd * 8];
        int k = (u * 3 + v) * 32 + qd * 8;
        bf16x8 b0 = *(const bf16x8*)&w_s[ml * 296 + k];
        bf16x8 b1 = *(const bf16x8*)&w_s[(16 + ml) * 296 + k];
        acc0 = __builtin_amdgcn_mfma_f32_16x16x32_bf16(af, b0, acc0, 0, 0, 0);
        acc1 = __builtin_amdgcn_mfma_f32_16x16x32_bf16(af, b1, acc1, 0, 0, 0);
    }
    float bia0 = bias[ml], bia1 = bias[16 + ml];
    float g0 = cnw[ml], g1 = cnw[16 + ml];
    float be0 = cnb[ml], be1 = cnb[16 + ml];
    #pragma unroll
    for (int r = 0; r < 4; r++) {
        float c0 = acc0[r] + bia0;
        float c1 = acc1[r] + bia1;
        float s = c0 + c1, q = c0 * c0 + c1 * c1;
        #pragma unroll
        for (int o = 8; o; o >>= 1) { s += __shfl_xor(s, o); q += __shfl_xor(q, o); }
        float mean = s * (1.f / 32.f);
        float inv = rsqrtf(q * (1.f / 32.f) - mean * mean + EPSc);
        int mr = wave * 16 + qd * 4 + r;
        int ry = ty * 8 + (mr >> 3), rx = tx * 8 + (mr & 7);
        bf16* op = attn_cat + ((size_t)b * Nc + ry * 56 + rx) * 128 + 96;
        op[ml]      = __float2bfloat16(gelu_f((c0 - mean) * inv * g0 + be0));
        op[16 + ml] = __float2bfloat16(gelu_f((c1 - mean) * inv * g1 + be1));
    }
}

// ---------------- merged sr: both depthwise reductions in one launch
template<int KS, int LD>
__device__ __forceinline__ void sr_body(int t, const float* __restrict__ xa,
        const float* __restrict__ wt, const float* __restrict__ bias,
        float* __restrict__ outp)
{
    int c = t % Cac; int r = t / Cac;
    int j = r % LD; r /= LD;
    int i = r % LD; int b = r / LD;
    float acc = bias[c];
    for (int u = 0; u < KS; u++)
        for (int v = 0; v < KS; v++)
            acc += xa[(size_t)(b * Nc + (i * KS + u) * Wcc + (j * KS + v)) * Cac + c]
                 * wt[(u * KS + v) * Cac + c];
    outp[t] = acc;
}

__global__ void sr_all_kernel(const float* __restrict__ xa,
        const float* __restrict__ sr1w, const float* __restrict__ sr1b, float* __restrict__ x1p,
        const float* __restrict__ sr2w, const float* __restrict__ sr2b, float* __restrict__ x2p)
{
    int t = blockIdx.x * blockDim.x + threadIdx.x;
    if (t < 150528) sr_body<8, 7>(t, xa, sr1w, sr1b, x1p);
    else {
        int u = t - 150528;
        if (u < 602112) sr_body<4, 14>(u, xa, sr2w, sr2b, x2p);
    }
}

// ---------------- merged LN over 96 + gelu -> bf16 (both branches, one launch)
__global__ __launch_bounds__(256) void ln96_all_kernel(
        const float* __restrict__ s1, const float* __restrict__ g1,
        const float* __restrict__ b1, bf16* __restrict__ d1,
        const float* __restrict__ s2, const float* __restrict__ g2,
        const float* __restrict__ b2, bf16* __restrict__ d2)
{
    int wv = threadIdx.x >> 6, lane = threadIdx.x & 63;
    int row = blockIdx.x * 4 + wv;
    const float* sp; const float* g; const float* be; bf16* dst; int r;
    if (row < 1568)      { sp = s1; g = g1; be = b1; dst = d1; r = row; }
    else if (row < 7840) { sp = s2; g = g2; be = b2; dst = d2; r = row - 1568; }
    else return;
    sp += (size_t)r * 96;
    float x0 = sp[lane];
    float x1 = (lane < 32) ? sp[64 + lane] : 0.f;
    float s = x0 + x1, q = x0 * x0 + x1 * x1;
    for (int o = 32; o; o >>= 1) { s += __shfl_xor(s, o); q += __shfl_xor(q, o); }
    float mean = s * (1.f / 96.f);
    float inv = rsqrtf(q * (1.f / 96.f) - mean * mean + EPSc);
    dst[(size_t)r * 96 + lane] =
        __float2bfloat16(gelu_f((x0 - mean) * inv * g[lane] + be[lane]));
    if (lane < 32)
        dst[(size_t)r * 96 + 64 + lane] =
            __float2bfloat16(gelu_f((x1 - mean) * inv * g[64 + lane] + be[64 + lane]));
}

// ---------------- GEMM body (MR=1, NF=6, BK=32), shared by the merged q/kv kernel.
// OMODE: 0 = fp32 row-major, 2 = fp32 head-major Q layout (B,8,N,12)
template<int OMODE>
__device__ __forceinline__ void qkv_body(const bf16* __restrict__ A,
        const bf16* __restrict__ Wt, void* __restrict__ outp,
        int M, int m0, unsigned short (*As)[40], unsigned short (*Bs)[40], int tid)
{
    const int K = 96, Nt = 96;
    int wave = tid >> 6, lane = tid & 63;
    f32x4 acc[6];
    #pragma unroll
    for (int f = 0; f < 6; f++) acc[f] = (f32x4){0.f, 0.f, 0.f, 0.f};
    int ar = tid >> 2, ac = (tid & 3) << 3;
    int ml = wave * 16 + (lane & 15);
    int qd = lane >> 4;
    for (int k0 = 0; k0 < K; k0 += 32) {
        int4 av = make_int4(0, 0, 0, 0);
        if (m0 + ar < M) av = *(const int4*)(A + (size_t)(m0 + ar) * K + k0 + ac);
        *(int4*)&As[ar][ac] = av;
        for (int idx = tid; idx < 384; idx += 256) {
            int br = idx >> 2, bc = (idx & 3) << 3;
            *(int4*)&Bs[br][bc] = *(const int4*)(Wt + (size_t)br * K + k0 + bc);
        }
        __syncthreads();
        bf16x8 af = *(const bf16x8*)&As[ml][qd * 8];
        #pragma unroll
        for (int f = 0; f < 6; f++) {
            bf16x8 bfv = *(const bf16x8*)&Bs[f * 16 + (lane & 15)][qd * 8];
            acc[f] = __builtin_amdgcn_mfma_f32_16x16x32_bf16(af, bfv, acc[f], 0, 0, 0);
        }
        __syncthreads();
    }
    #pragma unroll
    for (int f = 0; f < 6; f++) {
        int n = f * 16 + (lane & 15);
        #pragma unroll
        for (int r = 0; r < 4; r++) {
            int m = m0 + wave * 16 + qd * 4 + r;
            if (m >= M) continue;
            float v = acc[f][r];
            if (OMODE == 2) {
                int b = m / Nc, nn = m - b * Nc;
                int h = n / 12, d = n - h * 12;
                ((float*)outp)[(((size_t)(b * 8 + h)) * Nc + nn) * 12 + d] = v;
            } else
                ((float*)outp)[(size_t)m * Nt + n] = v;
        }
    }
}

// ---------------- merged q + kv1 + kv2 GEMMs (one launch, 1691 blocks)
__global__ __launch_bounds__(256) void qkv_kernel(
        const bf16* __restrict__ XAb,  const bf16* __restrict__ qwt,   float* __restrict__ QB,
        const bf16* __restrict__ X1Bb, const bf16* __restrict__ kv1wt, float* __restrict__ KV1,
        const bf16* __restrict__ X2Bb, const bf16* __restrict__ kv2wt, float* __restrict__ KV2)
{
    __shared__ unsigned short As[64][40];
    __shared__ unsigned short Bs[96][40];
    int by = blockIdx.x;
    int tid = threadIdx.x;
    if (by < 1568)      qkv_body<2>(XAb,  qwt,   QB,  100352, by * 64,          As, Bs, tid);
    else if (by < 1593) qkv_body<0>(X1Bb, kv1wt, KV1, 1568,   (by - 1568) * 64, As, Bs, tid);
    else                qkv_body<0>(X2Bb, kv2wt, KV2, 6272,   (by - 1593) * 64, As, Bs, tid);
}

// ---------------- MFMA GEMM (MR=1, templated K-depth BK). OMODE: 0 = fp32
// row-major, 1 = bf16 row-major
template<int NF, int BK, bool GELU, bool RES, int OMODE>
__global__ __launch_bounds__(256) void gemm_kernel(const bf16* __restrict__ A,
        const bf16* __restrict__ Wt, const float* __restrict__ bias,
        const float* __restrict__ res, void* __restrict__ outp,
        int M, int K, int Nt)
{
    constexpr int TN = 16 * NF;
    __shared__ unsigned short As[64][BK + 8];
    __shared__ unsigned short Bs[TN][BK + 8];
    int tid = threadIdx.x;
    int wave = tid >> 6, lane = tid & 63;
    int m0 = blockIdx.y * 64, n0 = blockIdx.x * TN;
    f32x4 acc[NF];
    #pragma unroll
    for (int f = 0; f < NF; f++) acc[f] = (f32x4){0.f, 0.f, 0.f, 0.f};

    int ar = tid >> 2, ac = (tid & 3) << 3;
    int ml = wave * 16 + (lane & 15);
    int qd = lane >> 4;

    for (int k0 = 0; k0 < K; k0 += BK) {
        #pragma unroll
        for (int i = 0; i < BK / 32; i++) {
            int cc = ac + i * 32;
            int4 av = make_int4(0, 0, 0, 0);
            if (m0 + ar < M) av = *(const int4*)(A + (size_t)(m0 + ar) * K + k0 + cc);
            *(int4*)&As[ar][cc] = av;
        }
        for (int idx = tid; idx < TN * (BK / 8); idx += 256) {
            int br = idx / (BK / 8), bc = (idx % (BK / 8)) * 8;
            *(int4*)&Bs[br][bc] = *(const int4*)(Wt + (size_t)(n0 + br) * K + k0 + bc);
        }
        __syncthreads();
        #pragma unroll
        for (int kk = 0; kk < BK / 32; kk++) {
            bf16x8 af = *(const bf16x8*)&As[ml][kk * 32 + qd * 8];
            #pragma unroll
            for (int f = 0; f < NF; f++) {
                bf16x8 bfv = *(const bf16x8*)&Bs[f * 16 + (lane & 15)][kk * 32 + qd * 8];
                acc[f] = __builtin_amdgcn_mfma_f32_16x16x32_bf16(af, bfv, acc[f], 0, 0, 0);
            }
        }
        __syncthreads();
    }
    #pragma unroll
    for (int f = 0; f < NF; f++) {
        int n = n0 + f * 16 + (lane & 15);
        #pragma unroll
        for (int r = 0; r < 4; r++) {
            int m = m0 + wave * 16 + qd * 4 + r;
            if (m >= M) continue;
            float v = acc[f][r];
            if (bias) v += bias[n];
            if (GELU) v = gelu_f(v);
            if (RES)  v += res[(size_t)m * Nt + n];
            if (OMODE == 1)
                ((bf16*)outp)[(size_t)m * Nt + n] = __float2bfloat16(v);
            else
                ((float*)outp)[(size_t)m * Nt + n] = v;
        }
    }
}

// ---------------- proj GEMM (K=128, TN=128 full rows) + bias + residual + FUSED LN2.
__global__ __launch_bounds__(256) void proj_ln_kernel(const bf16* __restrict__ A,
        const bf16* __restrict__ Wt, const float* __restrict__ bias,
        const float* __restrict__ res, const float* __restrict__ g,
        const float* __restrict__ be, float* __restrict__ xres, bf16* __restrict__ xnb)
{
    __shared__ unsigned short As[64][72];
    __shared__ unsigned short Bs[128][72];
    int tid = threadIdx.x;
    int wave = tid >> 6, lane = tid & 63;
    int m0 = blockIdx.x * 64;
    f32x4 acc[8];
    #pragma unroll
    for (int f = 0; f < 8; f++) acc[f] = (f32x4){0.f, 0.f, 0.f, 0.f};

    int ar = tid >> 2, ac = (tid & 3) << 3;
    int ml = lane & 15, qd = lane >> 4;
    int mlw = wave * 16 + ml;

    for (int k0 = 0; k0 < 128; k0 += 64) {
        #pragma unroll
        for (int i = 0; i < 2; i++) {
            int cc = ac + i * 32;
            *(int4*)&As[ar][cc] = *(const int4*)(A + (size_t)(m0 + ar) * 128 + k0 + cc);
        }
        for (int idx = tid; idx < 1024; idx += 256) {
            int br = idx >> 3, bc = (idx & 7) * 8;
            *(int4*)&Bs[br][bc] = *(const int4*)(Wt + (size_t)br * 128 + k0 + bc);
        }
        __syncthreads();
        #pragma unroll
        for (int kk = 0; kk < 2; kk++) {
            bf16x8 af = *(const bf16x8*)&As[mlw][kk * 32 + qd * 8];
            #pragma unroll
            for (int f = 0; f < 8; f++) {
                bf16x8 bfv = *(const bf16x8*)&Bs[f * 16 + ml][kk * 32 + qd * 8];
                acc[f] = __builtin_amdgcn_mfma_f32_16x16x32_bf16(af, bfv, acc[f], 0, 0, 0);
            }
        }
        __syncthreads();
    }
    float bia[8], gg[8], bb[8];
    #pragma unroll
    for (int f = 0; f < 8; f++) {
        int n = f * 16 + ml;
        bia[f] = bias[n]; gg[f] = g[n]; bb[f] = be[n];
    }
    #pragma unroll
    for (int r = 0; r < 4; r++) {
        int m = m0 + wave * 16 + qd * 4 + r;
        float vv[8];
        float s = 0.f, q = 0.f;
        #pragma unroll
        for (int f = 0; f < 8; f++) {
            int n = f * 16 + ml;
            float v = acc[f][r] + bia[f] + res[(size_t)m * 128 + n];
            vv[f] = v; s += v; q += v * v;
        }
        #pragma unroll
        for (int o = 8; o; o >>= 1) { s += __shfl_xor(s, o); q += __shfl_xor(q, o); }
        float mean = s * (1.f / 128.f);
        float inv = rsqrtf(q * (1.f / 128.f) - mean * mean + EPSc);
        #pragma unroll
        for (int f = 0; f < 8; f++) {
            int n = f * 16 + ml;
            xres[(size_t)m * 128 + n] = vv[f];
            xnb[(size_t)m * 128 + n] =
                __float2bfloat16((vv[f] - mean) * inv * gg[f] + bb[f]);
        }
    }
}

// ---------------- attention body: round-1 proven shape + raw v_exp_f32 (125us):
// fp32 K/V in LDS, 1 query/thread, branchless single-pass softmax.
template<int L>
__device__ __forceinline__ void attn_body(const float* __restrict__ qh,
        const float* __restrict__ kv, int hl, int h, int b,
        float* kb, float* vb, bf16* __restrict__ attn_cat)
{
    for (int idx = threadIdx.x; idx < L * 3; idx += 256) {
        int l = idx / 3, f = idx % 3;
        const float4* kp = (const float4*)(kv + (size_t)(b * L + l) * 96 + hl * 12) + f;
        float4 kk = kp[0];
        float4 vv = kp[12];
        *(float4*)&kb[l * 12 + f * 4] = kk;
        *(float4*)&vb[l * 12 + f * 4] = vv;
    }
    int n = blockIdx.x * 256 + threadIdx.x;
    bool act = (n < Nc);
    int nn = act ? n : (Nc - 1);
    const float4* qp = (const float4*)(qh + (((size_t)(b * 8 + h)) * Nc + nn) * 12);
    float4 q0 = qp[0], q1 = qp[1], q2 = qp[2];
    const float PRE = SCALEc * 1.4426950408889634f;   /* scale * log2(e) */
    q0.x *= PRE; q0.y *= PRE; q0.z *= PRE; q0.w *= PRE;
    q1.x *= PRE; q1.y *= PRE; q1.z *= PRE; q1.w *= PRE;
    q2.x *= PRE; q2.y *= PRE; q2.z *= PRE; q2.w *= PRE;
    __syncthreads();

    float den = 0.f;
    float o[12];
    #pragma unroll
    for (int d = 0; d < 12; d++) o[d] = 0.f;

    #pragma unroll 4
    for (int l = 0; l < L; l++) {
        const float4 k0 = *(const float4*)&kb[l * 12];
        const float4 k1 = *(const float4*)&kb[l * 12 + 4];
        const float4 k2 = *(const float4*)&kb[l * 12 + 8];
        float s0 = q0.x * k0.x + q0.y * k0.y + q0.z * k0.z + q0.w * k0.w;
        float s1 = q1.x * k1.x + q1.y * k1.y + q1.z * k1.z + q1.w * k1.w;
        float s2 = q2.x * k2.x + q2.y * k2.y + q2.z * k2.z + q2.w * k2.w;
        float e = fast_exp2(s0 + s1 + s2);
        den += e;
        const float4 v0 = *(const float4*)&vb[l * 12];
        const float4 v1 = *(const float4*)&vb[l * 12 + 4];
        const float4 v2 = *(const float4*)&vb[l * 12 + 8];
        o[0] += e * v0.x; o[1]  += e * v0.y; o[2]  += e * v0.z; o[3]  += e * v0.w;
        o[4] += e * v1.x; o[5]  += e * v1.y; o[6]  += e * v1.z; o[7]  += e * v1.w;
        o[8] += e * v2.x; o[9]  += e * v2.y; o[10] += e * v2.z; o[11] += e * v2.w;
    }
    if (act) {
        float rden = 1.f / den;
        bf16* op = attn_cat + (size_t)(b * Nc + n) * 128 + h * 12;
        #pragma unroll
        for (int d = 0; d < 12; d++) op[d] = __float2bfloat16(o[d] * rden);
    }
}

__global__ __launch_bounds__(256) void attn_kernel(const float* __restrict__ qh,
        const float* __restrict__ kv1, const float* __restrict__ kv2,
        bf16* __restrict__ attn_cat)
{
    __shared__ float kb[196 * 12];
    __shared__ float vb[196 * 12];
    int h = blockIdx.y, b = blockIdx.z;
    if (h < 4) attn_body<49> (qh, kv1, h,     h, b, kb, vb, attn_cat);
    else       attn_body<196>(qh, kv2, h - 4, h, b, kb, vb, attn_cat);
}

extern "C" void kernel_launch(void* const* d_in, const int* in_sizes, int n_in,
                              void* d_out, int out_size, void* d_ws, size_t ws_size,
                              hipStream_t stream)
{
    const float* x    = (const float*)d_in[0];
    const float* ln1w = (const float*)d_in[3];
    const float* ln1b = (const float*)d_in[4];
    const float* ln2w = (const float*)d_in[5];
    const float* ln2b = (const float*)d_in[6];
    const float* qw   = (const float*)d_in[7];
    const float* kv1w = (const float*)d_in[8];
    const float* kv2w = (const float*)d_in[9];
    const float* sr1w = (const float*)d_in[10];
    const float* sr1b = (const float*)d_in[11];
    const float* sr2w = (const float*)d_in[12];
    const float* sr2b = (const float*)d_in[13];
    const float* an1w = (const float*)d_in[14];
    const float* an1b = (const float*)d_in[15];
    const float* an2w = (const float*)d_in[16];
    const float* an2b = (const float*)d_in[17];
    const float* wbw  = (const float*)d_in[18];
    const float* wbb  = (const float*)d_in[19];
    const float* wbs  = (const float*)d_in[20];
    const float* wavw = (const float*)d_in[21];
    const float* wavs = (const float*)d_in[22];
    const float* cpw  = (const float*)d_in[23];
    const float* cpb  = (const float*)d_in[24];
    const float* cnw  = (const float*)d_in[25];
    const float* cnb  = (const float*)d_in[26];
    const float* pw   = (const float*)d_in[27];
    const float* pb   = (const float*)d_in[28];
    const float* f1w  = (const float*)d_in[29];
    const float* f1b  = (const float*)d_in[30];
    const float* f2w  = (const float*)d_in[31];
    const float* f2b  = (const float*)d_in[32];
    float* dout = (float*)d_out;
    float* ws = (float*)d_ws;

    float* XA    = ws;                      // 9,633,792
    float* QB    = ws + 9633792;            // head-major Q (B,8,N,12)
    float* XRES  = ws;                      // overlay
    bf16*  XNb   = (bf16*)(ws + 12845056);
    bf16*  XAb   = (bf16*)(ws + 19267584);
    bf16*  ACATb = (bf16*)(ws + 24084480);
    float* XCI   = ws + 30507008;
    float* SUB   = ws + 33718272;
    float* TT    = ws + 38014976;
    float* X1P   = ws + 48734208;
    float* X2P   = ws + 48884736;
    bf16*  X1Bb  = (bf16*)(ws + 49486848);
    bf16*  X2Bb  = (bf16*)(ws + 49562112);
    float* KV1   = ws + 49863168;
    float* KV2   = ws + 50013696;
    bf16*  WTB   = (bf16*)(ws + 50615808);
    bf16*  qwt   = WTB;
    bf16*  kv1wt = WTB + 9216;
    bf16*  kv2wt = WTB + 18432;
    bf16*  pwt   = WTB + 27648;
    bf16*  w1t   = WTB + 44032;
    bf16*  w2t   = WTB + 109568;
    bf16*  cpwt  = WTB + 175104;
    bf16*  Hb    = (bf16*)(ws + 24084480);  // overlays ACATb (dead after proj)
    bf16*  CIMGb = (bf16*)SUB;
    float* S0 = SUB;            float* T0 = TT;
    float* S1 = SUB + 3211264;  float* T1 = TT + 3211264;
    float* S2 = SUB + 4014080;  float* T2 = TT + 4014080;
    float* S3 = SUB + 4214784;  float* T3 = TT + 4214784;
    float* S4 = SUB + 4280320;  float* T4 = TT + 4280320;

    // 0. weight preps (single merged launch)
    wprep_kernel<<<720, 256, 0, stream>>>(qw, kv1w, kv2w, pw, f1w, f2w, cpw,
                                          qwt, kv1wt, kv2wt, pwt, w1t, w2t, cpwt);

    // 1. LN1
    ln1_kernel<<<25088, 256, 0, stream>>>(x, ln1w, ln1b, XA, XAb, XCI);

    // 2. Full DWT cascade (levels 0-4), one launch
    dwt_all_kernel<<<1024, 256, 0, stream>>>(XCI, S0, S1, S2, S3, S4);

    // 3. ALL wavelet depthwise convs in one launch
    dw3x3_all_kernel<<<16784, 256, 0, stream>>>(SUB, wavw, wavs, TT);

    // 4. Full IDWT cascade (levels 4-1) + level-0 + base conv, one launch
    idwt_all_dwbase_kernel<<<1024, 256, 0, stream>>>(T4, T3, T2, T1, T0, XCI,
                                                     wbw, wbs, wbb, CIMGb);

    // 5. cp2d implicit-GEMM MFMA + fused cn -> ACATb[96:128]
    cp2d_cn_kernel<<<dim3(49, 32), 256, 0, stream>>>(CIMGb, cpwt, cpb, cnw, cnb, ACATb);

    // 6. merged spatial reductions
    sr_all_kernel<<<2940, 256, 0, stream>>>(XA, sr1w, sr1b, X1P, sr2w, sr2b, X2P);

    // 7. merged LN96 + gelu -> bf16
    ln96_all_kernel<<<1960, 256, 0, stream>>>(X1P, an1w, an1b, X1Bb,
                                              X2P, an2w, an2b, X2Bb);

    // 8. merged q + kv1 + kv2 GEMMs (one launch)
    qkv_kernel<<<1691, 256, 0, stream>>>(XAb, qwt, QB, X1Bb, kv1wt, KV1, X2Bb, kv2wt, KV2);

    // 9. merged attention -> ACATb[0:96]
    attn_kernel<<<dim3(13, 8, 32), 256, 0, stream>>>(QB, KV1, KV2, ACATb);

    // 10. proj + bias + residual(x) + FUSED LN2 -> XRES fp32 + XNb bf16
    proj_ln_kernel<<<1568, 256, 0, stream>>>(ACATb, pwt, pb, x, ln2w, ln2b, XRES, XNb);

    // 11. fc1 + bias + gelu -> Hb bf16  (BK=64; proven)
    gemm_kernel<4,64,true,false,1><<<dim3(8, 1568), 256, 0, stream>>>(XNb, w1t, f1b, nullptr, Hb, 100352, 128, 512);

    // 12. fc2 + bias + residual(XRES) -> d_out fp32  (proven shape)
    gemm_kernel<4,64,false,true,0><<<dim3(2, 1568), 256, 0, stream>>>(Hb, w2t, f2b, XRES, dout, 100352, 512, 128);
}

// Round 16
// 565.607 us; speedup vs baseline: 1.0946x; 1.0079x over previous
//
#include <hip/hip_runtime.h>
#include <hip/hip_bf16.h>
#include <math.h>

typedef __hip_bfloat16 bf16;
typedef __attribute__((ext_vector_type(8))) short bf16x8;
typedef __attribute__((ext_vector_type(4))) float f32x4;

#define Bc   32
#define Hc   56
#define Wcc  56
#define Nc   3136
#define Cpc  32
#define Cac  96
#define EPSc 1e-5f
#define SCALEc 0.28867513459481287f   /* 1/sqrt(12) */

__device__ __forceinline__ float gelu_f(float x) {
    return 0.5f * x * (1.0f + erff(x * 0.7071067811865475f));
}

// raw v_exp_f32 (2^x). Fallback keeps correctness if builtin is absent.
__device__ __forceinline__ float fast_exp2(float x) {
#if defined(__has_builtin)
#if __has_builtin(__builtin_amdgcn_exp2f)
    return __builtin_amdgcn_exp2f(x);
#else
    return exp2f(x);
#endif
#else
    return exp2f(x);
#endif
}

// ---------------- LN1 (blocks 0..25087) + weight prep (blocks 25088..25807), one launch
__global__ __launch_bounds__(256) void ln1_wprep_kernel(const float* __restrict__ x,
        const float* __restrict__ g, const float* __restrict__ be,
        float* __restrict__ xa, bf16* __restrict__ xab, float* __restrict__ xc_img,
        const float* __restrict__ qw, const float* __restrict__ kv1w,
        const float* __restrict__ kv2w, const float* __restrict__ pw,
        const float* __restrict__ f1w, const float* __restrict__ f2w,
        const float* __restrict__ cpw, bf16* __restrict__ qwt, bf16* __restrict__ kv1wt,
        bf16* __restrict__ kv2wt, bf16* __restrict__ pwt, bf16* __restrict__ w1t,
        bf16* __restrict__ w2t, bf16* __restrict__ cpwt)
{
    if (blockIdx.x < 25088) {
        int wv = threadIdx.x >> 6, lane = threadIdx.x & 63;
        int row = blockIdx.x * 4 + wv;
        if (row >= Bc * Nc) return;
        const float* xr = x + (size_t)row * 128;
        float x0 = xr[lane];
        float x1 = xr[lane + 64];
        float s = x0 + x1, q = x0 * x0 + x1 * x1;
        for (int o = 32; o; o >>= 1) { s += __shfl_xor(s, o); q += __shfl_xor(q, o); }
        float mean = s * (1.f / 128.f);
        float inv = rsqrtf(q * (1.f / 128.f) - mean * mean + EPSc);
        int b = row / Nc, n = row % Nc;
        {
            int c = lane;
            float y = (x0 - mean) * inv * g[c] + be[c];
            if (c < Cpc) xc_img[(size_t)(b * Cpc + c) * Nc + n] = y;
            else { xa[(size_t)row * Cac + (c - Cpc)] = y;
                   xab[(size_t)row * Cac + (c - Cpc)] = __float2bfloat16(y); }
        }
        {
            int c = lane + 64;
            float y = (x1 - mean) * inv * g[c] + be[c];
            xa[(size_t)row * Cac + (c - Cpc)] = y;
            xab[(size_t)row * Cac + (c - Cpc)] = __float2bfloat16(y);
        }
    } else {
        int t = (blockIdx.x - 25088) * 256 + threadIdx.x;
        if (t < 9216) {
            int n = t % 96, k = t / 96;
            qwt[n * 96 + k] = __float2bfloat16(qw[t]);
        } else if (t < 18432) {
            int u = t - 9216; int n = u % 96, k = u / 96;
            kv1wt[n * 96 + k] = __float2bfloat16(kv1w[u]);
        } else if (t < 27648) {
            int u = t - 18432; int n = u % 96, k = u / 96;
            kv2wt[n * 96 + k] = __float2bfloat16(kv2w[u]);
        } else if (t < 44032) {
            int u = t - 27648; int n = u % 128, k = u / 128;
            pwt[n * 128 + k] = __float2bfloat16(pw[u]);
        } else if (t < 109568) {
            int u = t - 44032; int n = u % 512, k = u / 512;
            w1t[(size_t)n * 128 + k] = __float2bfloat16(f1w[u]);
        } else if (t < 175104) {
            int u = t - 109568; int n = u % 128, k = u / 128;
            w2t[(size_t)n * 512 + k] = __float2bfloat16(f2w[u]);
        } else if (t < 184320) {
            int u = t - 175104; int co = u / 288, k = u % 288;
            cpwt[u] = __float2bfloat16(cpw[k * 32 + co]);
        }
    }
}

// ---------------- FUSED DWT all 5 levels: one block per (b,c) plane; XCI plane
// staged in LDS; LL cascades through ping-pong buffers.
__global__ __launch_bounds__(256) void dwt_all_kernel(const float* __restrict__ xci,
        float* __restrict__ S0, float* __restrict__ S1, float* __restrict__ S2,
        float* __restrict__ S3, float* __restrict__ S4)
{
    __shared__ float bufA[3136];
    __shared__ float bufB[784];
    int bc = blockIdx.x; int b = bc >> 5, c = bc & 31;
    int t = threadIdx.x;
    const float* src = xci + (size_t)(b * 32 + c) * 3136;
    for (int i = t; i < 3136; i += 256) bufA[i] = src[i];
    __syncthreads();
    // level 0: 56x56 -> 28x28
    for (int p = t; p < 784; p += 256) {
        int yy = p / 28, xx = p % 28;
        int y0 = yy * 2, x0 = xx * 2;
        float a = bufA[y0 * 56 + x0],        bb = bufA[y0 * 56 + x0 + 1];
        float cc = bufA[(y0 + 1) * 56 + x0], dd = bufA[(y0 + 1) * 56 + x0 + 1];
        size_t ob = (size_t)(b * 128 + c * 4) * 784 + p;
        float vll = (a + bb + cc + dd) * 0.5f;
        S0[ob]         = vll;
        S0[ob + 784]   = (-a - bb + cc + dd) * 0.5f;
        S0[ob + 1568]  = (-a + bb - cc + dd) * 0.5f;
        S0[ob + 2352]  = ( a - bb - cc + dd) * 0.5f;
        bufB[p] = vll;
    }
    __syncthreads();
    // level 1: 28x28 -> 14x14
    for (int p = t; p < 196; p += 256) {
        int yy = p / 14, xx = p % 14;
        int y0 = yy * 2, x0 = xx * 2;
        float a = bufB[y0 * 28 + x0],        bb = bufB[y0 * 28 + x0 + 1];
        float cc = bufB[(y0 + 1) * 28 + x0], dd = bufB[(y0 + 1) * 28 + x0 + 1];
        size_t ob = (size_t)(b * 128 + c * 4) * 196 + p;
        float vll = (a + bb + cc + dd) * 0.5f;
        S1[ob]       = vll;
        S1[ob + 196] = (-a - bb + cc + dd) * 0.5f;
        S1[ob + 392] = (-a + bb - cc + dd) * 0.5f;
        S1[ob + 588] = ( a - bb - cc + dd) * 0.5f;
        bufA[p] = vll;
    }
    __syncthreads();
    // level 2: 14x14 -> 7x7
    if (t < 49) {
        int yy = t / 7, xx = t % 7;
        int y0 = yy * 2, x0 = xx * 2;
        float a = bufA[y0 * 14 + x0],        bb = bufA[y0 * 14 + x0 + 1];
        float cc = bufA[(y0 + 1) * 14 + x0], dd = bufA[(y0 + 1) * 14 + x0 + 1];
        size_t ob = (size_t)(b * 128 + c * 4) * 49 + t;
        float vll = (a + bb + cc + dd) * 0.5f;
        S2[ob]       = vll;
        S2[ob + 49]  = (-a - bb + cc + dd) * 0.5f;
        S2[ob + 98]  = (-a + bb - cc + dd) * 0.5f;
        S2[ob + 147] = ( a - bb - cc + dd) * 0.5f;
        bufB[t] = vll;
    }
    __syncthreads();
    // level 3: 7x7 (odd, zero-pad) -> 4x4
    if (t < 16) {
        int yy = t >> 2, xx = t & 3;
        int y0 = yy * 2, x0 = xx * 2;
        bool xe = (x0 + 1 < 7), ye = (y0 + 1 < 7);
        float a  = bufB[y0 * 7 + x0];
        float bb = xe ? bufB[y0 * 7 + x0 + 1] : 0.f;
        float cc = ye ? bufB[(y0 + 1) * 7 + x0] : 0.f;
        float dd = (xe && ye) ? bufB[(y0 + 1) * 7 + x0 + 1] : 0.f;
        size_t ob = (size_t)(b * 128 + c * 4) * 16 + t;
        float vll = (a + bb + cc + dd) * 0.5f;
        S3[ob]      = vll;
        S3[ob + 16] = (-a - bb + cc + dd) * 0.5f;
        S3[ob + 32] = (-a + bb - cc + dd) * 0.5f;
        S3[ob + 48] = ( a - bb - cc + dd) * 0.5f;
        bufA[t] = vll;
    }
    __syncthreads();
    // level 4: 4x4 -> 2x2
    if (t < 4) {
        int yy = t >> 1, xx = t & 1;
        int y0 = yy * 2, x0 = xx * 2;
        float a = bufA[y0 * 4 + x0],        bb = bufA[y0 * 4 + x0 + 1];
        float cc = bufA[(y0 + 1) * 4 + x0], dd = bufA[(y0 + 1) * 4 + x0 + 1];
        size_t ob = (size_t)(b * 128 + c * 4) * 4 + t;
        S4[ob]      = ( a + bb + cc + dd) * 0.5f;
        S4[ob + 4]  = (-a - bb + cc + dd) * 0.5f;
        S4[ob + 8]  = (-a + bb - cc + dd) * 0.5f;
        S4[ob + 12] = ( a - bb - cc + dd) * 0.5f;
    }
}

// ---------------- merged wavelet depthwise 3x3 (all 5 levels, one launch)
template<int H>
__device__ __forceinline__ void dw3_body(int r, const float* __restrict__ src,
        const float* __restrict__ wt, const float* __restrict__ scale,
        float* __restrict__ dst)
{
    int x = r % H; int rr = r / H;
    int y = rr % H; rr /= H;
    int c = rr & 127;
    const float* sp = src + (r - x - y * H);
    float acc = 0.f;
    #pragma unroll
    for (int u = 0; u < 3; u++) {
        int yy = y + u - 1;
        if (yy < 0 || yy >= H) continue;
        #pragma unroll
        for (int v = 0; v < 3; v++) {
            int xx = x + v - 1;
            if (xx < 0 || xx >= H) continue;
            acc += sp[yy * H + xx] * wt[(u * 3 + v) * 128 + c];
        }
    }
    dst[r] = acc * scale[c];
}

__global__ void dw3x3_all_kernel(const float* __restrict__ sub, const float* __restrict__ wavw,
        const float* __restrict__ wavs, float* __restrict__ tt)
{
    int t = blockIdx.x * blockDim.x + threadIdx.x;
    if (t < 3211264)      dw3_body<28>(t,           sub,           wavw,        wavs,       tt);
    else if (t < 4014080) dw3_body<14>(t - 3211264, sub + 3211264, wavw + 1152, wavs + 128, tt + 3211264);
    else if (t < 4214784) dw3_body<7> (t - 4014080, sub + 4014080, wavw + 2304, wavs + 256, tt + 4014080);
    else if (t < 4280320) dw3_body<4> (t - 4214784, sub + 4214784, wavw + 3456, wavs + 384, tt + 4214784);
    else if (t < 4296704) dw3_body<2> (t - 4280320, sub + 4280320, wavw + 4608, wavs + 512, tt + 4280320);
}

// ---------------- FUSED IDWT levels 4..1 + level-0 + base depthwise conv.
__global__ __launch_bounds__(256) void idwt_all_dwbase_kernel(
        const float* __restrict__ T4, const float* __restrict__ T3,
        const float* __restrict__ T2, const float* __restrict__ T1,
        const float* __restrict__ T0, const float* __restrict__ xci,
        const float* __restrict__ wt, const float* __restrict__ scale,
        const float* __restrict__ bias, bf16* __restrict__ dst_nhwc)
{
    __shared__ float xs[3136];
    __shared__ float r28[784];
    __shared__ float rS[196];
    int bc = blockIdx.x; int b = bc >> 5, c = bc & 31;
    int t = threadIdx.x;
    const float* xsrc = xci + (size_t)(b * 32 + c) * 3136;
    for (int i = t; i < 3136; i += 256) xs[i] = xsrc[i];
    if (t < 16) {
        int y = t >> 2, x = t & 3;
        size_t base = (size_t)(b * 128 + c * 4) * 4 + (y >> 1) * 2 + (x >> 1);
        float ll = T4[base];
        float lh = T4[base + 4], hl = T4[base + 8], hh = T4[base + 12];
        float v;
        if ((y & 1) == 0) v = ((x & 1) == 0) ? (ll - lh - hl + hh) : (ll - lh + hl - hh);
        else              v = ((x & 1) == 0) ? (ll + lh - hl - hh) : (ll + lh + hl + hh);
        rS[t] = v * 0.5f;
    }
    __syncthreads();
    if (t < 49) {
        int y = t / 7, x = t % 7;
        int y2 = y >> 1, x2 = x >> 1;
        size_t base = (size_t)(b * 128 + c * 4) * 16 + y2 * 4 + x2;
        float ll = T3[base] + rS[y2 * 4 + x2];
        float lh = T3[base + 16], hl = T3[base + 32], hh = T3[base + 48];
        float v;
        if ((y & 1) == 0) v = ((x & 1) == 0) ? (ll - lh - hl + hh) : (ll - lh + hl - hh);
        else              v = ((x & 1) == 0) ? (ll + lh - hl - hh) : (ll + lh + hl + hh);
        r28[t] = v * 0.5f;
    }
    __syncthreads();
    if (t < 196) {
        int y = t / 14, x = t % 14;
        int y2 = y >> 1, x2 = x >> 1;
        size_t base = (size_t)(b * 128 + c * 4) * 49 + y2 * 7 + x2;
        float ll = T2[base] + r28[y2 * 7 + x2];
        float lh = T2[base + 49], hl = T2[base + 98], hh = T2[base + 147];
        float v;
        if ((y & 1) == 0) v = ((x & 1) == 0) ? (ll - lh - hl + hh) : (ll - lh + hl - hh);
        else              v = ((x & 1) == 0) ? (ll + lh - hl - hh) : (ll + lh + hl + hh);
        rS[t] = v * 0.5f;
    }
    __syncthreads();
    for (int p = t; p < 784; p += 256) {
        int y = p / 28, x = p % 28;
        int y2 = y >> 1, x2 = x >> 1;
        size_t base = (size_t)(b * 128 + c * 4) * 196 + y2 * 14 + x2;
        float ll = T1[base] + rS[y2 * 14 + x2];
        float lh = T1[base + 196], hl = T1[base + 392], hh = T1[base + 588];
        float v;
        if ((y & 1) == 0) v = ((x & 1) == 0) ? (ll - lh - hl + hh) : (ll - lh + hl - hh);
        else              v = ((x & 1) == 0) ? (ll + lh - hl - hh) : (ll + lh + hl + hh);
        r28[p] = v * 0.5f;
    }
    __syncthreads();
    float w9[9];
    #pragma unroll
    for (int i = 0; i < 9; i++) w9[i] = wt[i * 32 + c];
    float bia = bias[c], scl = scale[c];
    for (int p = t; p < 3136; p += 256) {
        int y = p / 56, x = p % 56;
        int y2 = y >> 1, x2 = x >> 1;
        size_t base = (size_t)(b * 128 + c * 4) * 784 + y2 * 28 + x2;
        float ll = T0[base] + r28[y2 * 28 + x2];
        float lh = T0[base + 784], hl = T0[base + 1568], hh = T0[base + 2352];
        float v;
        if ((y & 1) == 0) v = ((x & 1) == 0) ? (ll - lh - hl + hh) : (ll - lh + hl - hh);
        else              v = ((x & 1) == 0) ? (ll + lh - hl - hh) : (ll + lh + hl + hh);
        float recon = v * 0.5f;
        float acc = 0.f;
        #pragma unroll
        for (int u = 0; u < 3; u++) {
            int yy = y + u - 1;
            if (yy < 0 || yy >= 56) continue;
            #pragma unroll
            for (int vv = 0; vv < 3; vv++) {
                int xx = x + vv - 1;
                if (xx < 0 || xx >= 56) continue;
                acc += xs[yy * 56 + xx] * w9[u * 3 + vv];
            }
        }
        acc = (acc + bia) * scl + recon;
        dst_nhwc[(((size_t)b * 56 + y) * 56 + x) * 32 + c] = __float2bfloat16(acc);
    }
}

// ---------------- cp2d implicit-GEMM MFMA + FUSED cn (LN over 32 ch + gelu)
__global__ __launch_bounds__(256) void cp2d_cn_kernel(const bf16* __restrict__ src,
        const bf16* __restrict__ wtc, const float* __restrict__ bias,
        const float* __restrict__ cnw, const float* __restrict__ cnb,
        bf16* __restrict__ attn_cat)
{
    __shared__ unsigned short in_s[10 * 400];
    __shared__ unsigned short w_s[32 * 296];
    int tid = threadIdx.x;
    int b = blockIdx.y;
    int ty = blockIdx.x / 7, tx = blockIdx.x % 7;
    for (int idx = tid; idx < 1152; idx += 256) {
        int co = idx / 36, j8 = (idx % 36) * 8;
        *(int4*)&w_s[co * 296 + j8] = *(const int4*)(wtc + co * 288 + j8);
    }
    {
        int idx = tid;
        if (idx < 200) {
            int cell = idx >> 1, half = idx & 1;
            int dy = cell / 10, dx = cell % 10;
            int gy = ty * 8 - 1 + dy, gx = tx * 8 - 1 + dx;
            int4 v0 = make_int4(0, 0, 0, 0), v1 = v0;
            if (gy >= 0 && gy < 56 && gx >= 0 && gx < 56) {
                const int4* gp = (const int4*)(src + ((((size_t)b * 56 + gy) * 56 + gx) * 32 + half * 16));
                v0 = gp[0]; v1 = gp[1];
            }
            *(int4*)&in_s[dy * 400 + dx * 40 + half * 16] = v0;
            *(int4*)&in_s[dy * 400 + dx * 40 + half * 16 + 8] = v1;
        }
    }
    __syncthreads();
    int wave = tid >> 6, lane = tid & 63;
    int ml = lane & 15, qd = lane >> 4;
    int m = wave * 16 + ml;
    int ly = m >> 3, lx = m & 7;
    f32x4 acc0 = {0.f, 0.f, 0.f, 0.f}, acc1 = {0.f, 0.f, 0.f, 0.f};
    #pragma unroll
    for (int u = 0; u < 3; u++)
    #pragma unroll
    for (int v = 0; v < 3; v++) {
        bf16x8 af = *(const bf16x8*)&in_s[(ly + u) * 400 + (lx + v) * 40 + qd * 8];
        int k = (u * 3 + v) * 32 + qd * 8;
        bf16x8 b0 = *(const bf16x8*)&w_s[ml * 296 + k];
        bf16x8 b1 = *(const bf16x8*)&w_s[(16 + ml) * 296 + k];
        acc0 = __builtin_amdgcn_mfma_f32_16x16x32_bf16(af, b0, acc0, 0, 0, 0);
        acc1 = __builtin_amdgcn_mfma_f32_16x16x32_bf16(af, b1, acc1, 0, 0, 0);
    }
    float bia0 = bias[ml], bia1 = bias[16 + ml];
    float g0 = cnw[ml], g1 = cnw[16 + ml];
    float be0 = cnb[ml], be1 = cnb[16 + ml];
    #pragma unroll
    for (int r = 0; r < 4; r++) {
        float c0 = acc0[r] + bia0;
        float c1 = acc1[r] + bia1;
        float s = c0 + c1, q = c0 * c0 + c1 * c1;
        #pragma unroll
        for (int o = 8; o; o >>= 1) { s += __shfl_xor(s, o); q += __shfl_xor(q, o); }
        float mean = s * (1.f / 32.f);
        float inv = rsqrtf(q * (1.f / 32.f) - mean * mean + EPSc);
        int mr = wave * 16 + qd * 4 + r;
        int ry = ty * 8 + (mr >> 3), rx = tx * 8 + (mr & 7);
        bf16* op = attn_cat + ((size_t)b * Nc + ry * 56 + rx) * 128 + 96;
        op[ml]      = __float2bfloat16(gelu_f((c0 - mean) * inv * g0 + be0));
        op[16 + ml] = __float2bfloat16(gelu_f((c1 - mean) * inv * g1 + be1));
    }
}

// ---------------- FUSED sr + LN96 + gelu: one block per 2 rows (128 thr each,
// 96 active). sr accumulation identical to sr_body; LN stats via 64-lane
// shuffle + 2-wave LDS combine; writes bf16 directly (X1P/X2P eliminated).
__global__ __launch_bounds__(256) void sr_ln_kernel(const float* __restrict__ xa,
        const float* __restrict__ sr1w, const float* __restrict__ sr1b,
        const float* __restrict__ an1w, const float* __restrict__ an1b, bf16* __restrict__ d1,
        const float* __restrict__ sr2w, const float* __restrict__ sr2b,
        const float* __restrict__ an2w, const float* __restrict__ an2b, bf16* __restrict__ d2)
{
    __shared__ float part[2][2][2];   // [row-in-block][wave-in-row][s,q]
    int t = threadIdx.x;
    int sub = t >> 7;                 // row within block
    int lt  = t & 127;                // thread within row
    int row = blockIdx.x * 2 + sub;
    int c = lt;
    bool act = (c < 96);
    float acc = 0.f;
    const float* g; const float* be; bf16* dst; int outr;
    if (row < 1568) {
        int r = row; int j = r % 7; r /= 7; int i = r % 7; int b = r / 7;
        if (act) {
            acc = sr1b[c];
            for (int u = 0; u < 8; u++)
                for (int v = 0; v < 8; v++)
                    acc += xa[(size_t)(b * Nc + (i * 8 + u) * Wcc + (j * 8 + v)) * Cac + c]
                         * sr1w[(u * 8 + v) * Cac + c];
        }
        g = an1w; be = an1b; dst = d1; outr = row;
    } else {
        int r = row - 1568; int j = r % 14; r /= 14; int i = r % 14; int b = r / 14;
        if (act) {
            acc = sr2b[c];
            for (int u = 0; u < 4; u++)
                for (int v = 0; v < 4; v++)
                    acc += xa[(size_t)(b * Nc + (i * 4 + u) * Wcc + (j * 4 + v)) * Cac + c]
                         * sr2w[(u * 4 + v) * Cac + c];
        }
        g = an2w; be = an2b; dst = d2; outr = row - 1568;
    }
    float s = act ? acc : 0.f, q = act ? acc * acc : 0.f;
    for (int o = 32; o; o >>= 1) { s += __shfl_xor(s, o); q += __shfl_xor(q, o); }
    int wvr = (t >> 6) & 1;
    if ((t & 63) == 0) { part[sub][wvr][0] = s; part[sub][wvr][1] = q; }
    __syncthreads();
    if (act) {
        float st = part[sub][0][0] + part[sub][1][0];
        float qt = part[sub][0][1] + part[sub][1][1];
        float mean = st * (1.f / 96.f);
        float inv = rsqrtf(qt * (1.f / 96.f) - mean * mean + EPSc);
        dst[(size_t)outr * 96 + c] =
            __float2bfloat16(gelu_f((acc - mean) * inv * g[c] + be[c]));
    }
}

// ---------------- GEMM body (MR=1, NF=6, BK=32), shared by the merged q/kv kernel.
template<int OMODE>
__device__ __forceinline__ void qkv_body(const bf16* __restrict__ A,
        const bf16* __restrict__ Wt, void* __restrict__ outp,
        int M, int m0, unsigned short (*As)[40], unsigned short (*Bs)[40], int tid)
{
    const int K = 96, Nt = 96;
    int wave = tid >> 6, lane = tid & 63;
    f32x4 acc[6];
    #pragma unroll
    for (int f = 0; f < 6; f++) acc[f] = (f32x4){0.f, 0.f, 0.f, 0.f};
    int ar = tid >> 2, ac = (tid & 3) << 3;
    int ml = wave * 16 + (lane & 15);
    int qd = lane >> 4;
    for (int k0 = 0; k0 < K; k0 += 32) {
        int4 av = make_int4(0, 0, 0, 0);
        if (m0 + ar < M) av = *(const int4*)(A + (size_t)(m0 + ar) * K + k0 + ac);
        *(int4*)&As[ar][ac] = av;
        for (int idx = tid; idx < 384; idx += 256) {
            int br = idx >> 2, bc = (idx & 3) << 3;
            *(int4*)&Bs[br][bc] = *(const int4*)(Wt + (size_t)br * K + k0 + bc);
        }
        __syncthreads();
        bf16x8 af = *(const bf16x8*)&As[ml][qd * 8];
        #pragma unroll
        for (int f = 0; f < 6; f++) {
            bf16x8 bfv = *(const bf16x8*)&Bs[f * 16 + (lane & 15)][qd * 8];
            acc[f] = __builtin_amdgcn_mfma_f32_16x16x32_bf16(af, bfv, acc[f], 0, 0, 0);
        }
        __syncthreads();
    }
    #pragma unroll
    for (int f = 0; f < 6; f++) {
        int n = f * 16 + (lane & 15);
        #pragma unroll
        for (int r = 0; r < 4; r++) {
            int m = m0 + wave * 16 + qd * 4 + r;
            if (m >= M) continue;
            float v = acc[f][r];
            if (OMODE == 2) {
                int b = m / Nc, nn = m - b * Nc;
                int h = n / 12, d = n - h * 12;
                ((float*)outp)[(((size_t)(b * 8 + h)) * Nc + nn) * 12 + d] = v;
            } else
                ((float*)outp)[(size_t)m * Nt + n] = v;
        }
    }
}

// ---------------- merged q + kv1 + kv2 GEMMs (one launch, 1691 blocks)
__global__ __launch_bounds__(256) void qkv_kernel(
        const bf16* __restrict__ XAb,  const bf16* __restrict__ qwt,   float* __restrict__ QB,
        const bf16* __restrict__ X1Bb, const bf16* __restrict__ kv1wt, float* __restrict__ KV1,
        const bf16* __restrict__ X2Bb, const bf16* __restrict__ kv2wt, float* __restrict__ KV2)
{
    __shared__ unsigned short As[64][40];
    __shared__ unsigned short Bs[96][40];
    int by = blockIdx.x;
    int tid = threadIdx.x;
    if (by < 1568)      qkv_body<2>(XAb,  qwt,   QB,  100352, by * 64,          As, Bs, tid);
    else if (by < 1593) qkv_body<0>(X1Bb, kv1wt, KV1, 1568,   (by - 1568) * 64, As, Bs, tid);
    else                qkv_body<0>(X2Bb, kv2wt, KV2, 6272,   (by - 1593) * 64, As, Bs, tid);
}

// ---------------- MFMA GEMM (MR=1, templated K-depth BK)
template<int NF, int BK, bool GELU, bool RES, int OMODE>
__global__ __launch_bounds__(256) void gemm_kernel(const bf16* __restrict__ A,
        const bf16* __restrict__ Wt, const float* __restrict__ bias,
        const float* __restrict__ res, void* __restrict__ outp,
        int M, int K, int Nt)
{
    constexpr int TN = 16 * NF;
    __shared__ unsigned short As[64][BK + 8];
    __shared__ unsigned short Bs[TN][BK + 8];
    int tid = threadIdx.x;
    int wave = tid >> 6, lane = tid & 63;
    int m0 = blockIdx.y * 64, n0 = blockIdx.x * TN;
    f32x4 acc[NF];
    #pragma unroll
    for (int f = 0; f < NF; f++) acc[f] = (f32x4){0.f, 0.f, 0.f, 0.f};

    int ar = tid >> 2, ac = (tid & 3) << 3;
    int ml = wave * 16 + (lane & 15);
    int qd = lane >> 4;

    for (int k0 = 0; k0 < K; k0 += BK) {
        #pragma unroll
        for (int i = 0; i < BK / 32; i++) {
            int cc = ac + i * 32;
            int4 av = make_int4(0, 0, 0, 0);
            if (m0 + ar < M) av = *(const int4*)(A + (size_t)(m0 + ar) * K + k0 + cc);
            *(int4*)&As[ar][cc] = av;
        }
        for (int idx = tid; idx < TN * (BK / 8); idx += 256) {
            int br = idx / (BK / 8), bc = (idx % (BK / 8)) * 8;
            *(int4*)&Bs[br][bc] = *(const int4*)(Wt + (size_t)(n0 + br) * K + k0 + bc);
        }
        __syncthreads();
        #pragma unroll
        for (int kk = 0; kk < BK / 32; kk++) {
            bf16x8 af = *(const bf16x8*)&As[ml][kk * 32 + qd * 8];
            #pragma unroll
            for (int f = 0; f < NF; f++) {
                bf16x8 bfv = *(const bf16x8*)&Bs[f * 16 + (lane & 15)][kk * 32 + qd * 8];
                acc[f] = __builtin_amdgcn_mfma_f32_16x16x32_bf16(af, bfv, acc[f], 0, 0, 0);
            }
        }
        __syncthreads();
    }
    #pragma unroll
    for (int f = 0; f < NF; f++) {
        int n = n0 + f * 16 + (lane & 15);
        #pragma unroll
        for (int r = 0; r < 4; r++) {
            int m = m0 + wave * 16 + qd * 4 + r;
            if (m >= M) continue;
            float v = acc[f][r];
            if (bias) v += bias[n];
            if (GELU) v = gelu_f(v);
            if (RES)  v += res[(size_t)m * Nt + n];
            if (OMODE == 1)
                ((bf16*)outp)[(size_t)m * Nt + n] = __float2bfloat16(v);
            else
                ((float*)outp)[(size_t)m * Nt + n] = v;
        }
    }
}

// ---------------- proj GEMM (K=128, TN=128 full rows) + bias + residual + FUSED LN2.
__global__ __launch_bounds__(256) void proj_ln_kernel(const bf16* __restrict__ A,
        const bf16* __restrict__ Wt, const float* __restrict__ bias,
        const float* __restrict__ res, const float* __restrict__ g,
        const float* __restrict__ be, float* __restrict__ xres, bf16* __restrict__ xnb)
{
    __shared__ unsigned short As[64][72];
    __shared__ unsigned short Bs[128][72];
    int tid = threadIdx.x;
    int wave = tid >> 6, lane = tid & 63;
    int m0 = blockIdx.x * 64;
    f32x4 acc[8];
    #pragma unroll
    for (int f = 0; f < 8; f++) acc[f] = (f32x4){0.f, 0.f, 0.f, 0.f};

    int ar = tid >> 2, ac = (tid & 3) << 3;
    int ml = lane & 15, qd = lane >> 4;
    int mlw = wave * 16 + ml;

    for (int k0 = 0; k0 < 128; k0 += 64) {
        #pragma unroll
        for (int i = 0; i < 2; i++) {
            int cc = ac + i * 32;
            *(int4*)&As[ar][cc] = *(const int4*)(A + (size_t)(m0 + ar) * 128 + k0 + cc);
        }
        for (int idx = tid; idx < 1024; idx += 256) {
            int br = idx >> 3, bc = (idx & 7) * 8;
            *(int4*)&Bs[br][bc] = *(const int4*)(Wt + (size_t)br * 128 + k0 + bc);
        }
        __syncthreads();
        #pragma unroll
        for (int kk = 0; kk < 2; kk++) {
            bf16x8 af = *(const bf16x8*)&As[mlw][kk * 32 + qd * 8];
            #pragma unroll
            for (int f = 0; f < 8; f++) {
                bf16x8 bfv = *(const bf16x8*)&Bs[f * 16 + ml][kk * 32 + qd * 8];
                acc[f] = __builtin_amdgcn_mfma_f32_16x16x32_bf16(af, bfv, acc[f], 0, 0, 0);
            }
        }
        __syncthreads();
    }
    float bia[8], gg[8], bb[8];
    #pragma unroll
    for (int f = 0; f < 8; f++) {
        int n = f * 16 + ml;
        bia[f] = bias[n]; gg[f] = g[n]; bb[f] = be[n];
    }
    #pragma unroll
    for (int r = 0; r < 4; r++) {
        int m = m0 + wave * 16 + qd * 4 + r;
        float vv[8];
        float s = 0.f, q = 0.f;
        #pragma unroll
        for (int f = 0; f < 8; f++) {
            int n = f * 16 + ml;
            float v = acc[f][r] + bia[f] + res[(size_t)m * 128 + n];
            vv[f] = v; s += v; q += v * v;
        }
        #pragma unroll
        for (int o = 8; o; o >>= 1) { s += __shfl_xor(s, o); q += __shfl_xor(q, o); }
        float mean = s * (1.f / 128.f);
        float inv = rsqrtf(q * (1.f / 128.f) - mean * mean + EPSc);
        #pragma unroll
        for (int f = 0; f < 8; f++) {
            int n = f * 16 + ml;
            xres[(size_t)m * 128 + n] = vv[f];
            xnb[(size_t)m * 128 + n] =
                __float2bfloat16((vv[f] - mean) * inv * gg[f] + bb[f]);
        }
    }
}

// ---------------- attention body: round-1 proven shape + raw v_exp_f32 (125us):
template<int L>
__device__ __forceinline__ void attn_body(const float* __restrict__ qh,
        const float* __restrict__ kv, int hl, int h, int b,
        float* kb, float* vb, bf16* __restrict__ attn_cat)
{
    for (int idx = threadIdx.x; idx < L * 3; idx += 256) {
        int l = idx / 3, f = idx % 3;
        const float4* kp = (const float4*)(kv + (size_t)(b * L + l) * 96 + hl * 12) + f;
        float4 kk = kp[0];
        float4 vv = kp[12];
        *(float4*)&kb[l * 12 + f * 4] = kk;
        *(float4*)&vb[l * 12 + f * 4] = vv;
    }
    int n = blockIdx.x * 256 + threadIdx.x;
    bool act = (n < Nc);
    int nn = act ? n : (Nc - 1);
    const float4* qp = (const float4*)(qh + (((size_t)(b * 8 + h)) * Nc + nn) * 12);
    float4 q0 = qp[0], q1 = qp[1], q2 = qp[2];
    const float PRE = SCALEc * 1.4426950408889634f;
    q0.x *= PRE; q0.y *= PRE; q0.z *= PRE; q0.w *= PRE;
    q1.x *= PRE; q1.y *= PRE; q1.z *= PRE; q1.w *= PRE;
    q2.x *= PRE; q2.y *= PRE; q2.z *= PRE; q2.w *= PRE;
    __syncthreads();

    float den = 0.f;
    float o[12];
    #pragma unroll
    for (int d = 0; d < 12; d++) o[d] = 0.f;

    #pragma unroll 4
    for (int l = 0; l < L; l++) {
        const float4 k0 = *(const float4*)&kb[l * 12];
        const float4 k1 = *(const float4*)&kb[l * 12 + 4];
        const float4 k2 = *(const float4*)&kb[l * 12 + 8];
        float s0 = q0.x * k0.x + q0.y * k0.y + q0.z * k0.z + q0.w * k0.w;
        float s1 = q1.x * k1.x + q1.y * k1.y + q1.z * k1.z + q1.w * k1.w;
        float s2 = q2.x * k2.x + q2.y * k2.y + q2.z * k2.z + q2.w * k2.w;
        float e = fast_exp2(s0 + s1 + s2);
        den += e;
        const float4 v0 = *(const float4*)&vb[l * 12];
        const float4 v1 = *(const float4*)&vb[l * 12 + 4];
        const float4 v2 = *(const float4*)&vb[l * 12 + 8];
        o[0] += e * v0.x; o[1]  += e * v0.y; o[2]  += e * v0.z; o[3]  += e * v0.w;
        o[4] += e * v1.x; o[5]  += e * v1.y; o[6]  += e * v1.z; o[7]  += e * v1.w;
        o[8] += e * v2.x; o[9]  += e * v2.y; o[10] += e * v2.z; o[11] += e * v2.w;
    }
    if (act) {
        float rden = 1.f / den;
        bf16* op = attn_cat + (size_t)(b * Nc + n) * 128 + h * 12;
        #pragma unroll
        for (int d = 0; d < 12; d++) op[d] = __float2bfloat16(o[d] * rden);
    }
}

__global__ __launch_bounds__(256) void attn_kernel(const float* __restrict__ qh,
        const float* __restrict__ kv1, const float* __restrict__ kv2,
        bf16* __restrict__ attn_cat)
{
    __shared__ float kb[196 * 12];
    __shared__ float vb[196 * 12];
    int h = blockIdx.y, b = blockIdx.z;
    if (h < 4) attn_body<49> (qh, kv1, h,     h, b, kb, vb, attn_cat);
    else       attn_body<196>(qh, kv2, h - 4, h, b, kb, vb, attn_cat);
}

extern "C" void kernel_launch(void* const* d_in, const int* in_sizes, int n_in,
                              void* d_out, int out_size, void* d_ws, size_t ws_size,
                              hipStream_t stream)
{
    const float* x    = (const float*)d_in[0];
    const float* ln1w = (const float*)d_in[3];
    const float* ln1b = (const float*)d_in[4];
    const float* ln2w = (const float*)d_in[5];
    const float* ln2b = (const float*)d_in[6];
    const float* qw   = (const float*)d_in[7];
    const float* kv1w = (const float*)d_in[8];
    const float* kv2w = (const float*)d_in[9];
    const float* sr1w = (const float*)d_in[10];
    const float* sr1b = (const float*)d_in[11];
    const float* sr2w = (const float*)d_in[12];
    const float* sr2b = (const float*)d_in[13];
    const float* an1w = (const float*)d_in[14];
    const float* an1b = (const float*)d_in[15];
    const float* an2w = (const float*)d_in[16];
    const float* an2b = (const float*)d_in[17];
    const float* wbw  = (const float*)d_in[18];
    const float* wbb  = (const float*)d_in[19];
    const float* wbs  = (const float*)d_in[20];
    const float* wavw = (const float*)d_in[21];
    const float* wavs = (const float*)d_in[22];
    const float* cpw  = (const float*)d_in[23];
    const float* cpb  = (const float*)d_in[24];
    const float* cnw  = (const float*)d_in[25];
    const float* cnb  = (const float*)d_in[26];
    const float* pw   = (const float*)d_in[27];
    const float* pb   = (const float*)d_in[28];
    const float* f1w  = (const float*)d_in[29];
    const float* f1b  = (const float*)d_in[30];
    const float* f2w  = (const float*)d_in[31];
    const float* f2b  = (const float*)d_in[32];
    float* dout = (float*)d_out;
    float* ws = (float*)d_ws;

    float* XA    = ws;                      // 9,633,792
    float* QB    = ws + 9633792;            // head-major Q (B,8,N,12)
    float* XRES  = ws;                      // overlay
    bf16*  XNb   = (bf16*)(ws + 12845056);
    bf16*  XAb   = (bf16*)(ws + 19267584);
    bf16*  ACATb = (bf16*)(ws + 24084480);
    float* XCI   = ws + 30507008;
    float* SUB   = ws + 33718272;
    float* TT    = ws + 38014976;
    bf16*  X1Bb  = (bf16*)(ws + 49486848);
    bf16*  X2Bb  = (bf16*)(ws + 49562112);
    float* KV1   = ws + 49863168;
    float* KV2   = ws + 50013696;
    bf16*  WTB   = (bf16*)(ws + 50615808);
    bf16*  qwt   = WTB;
    bf16*  kv1wt = WTB + 9216;
    bf16*  kv2wt = WTB + 18432;
    bf16*  pwt   = WTB + 27648;
    bf16*  w1t   = WTB + 44032;
    bf16*  w2t   = WTB + 109568;
    bf16*  cpwt  = WTB + 175104;
    bf16*  Hb    = (bf16*)(ws + 24084480);  // overlays ACATb (dead after proj)
    bf16*  CIMGb = (bf16*)SUB;
    float* S0 = SUB;            float* T0 = TT;
    float* S1 = SUB + 3211264;  float* T1 = TT + 3211264;
    float* S2 = SUB + 4014080;  float* T2 = TT + 4014080;
    float* S3 = SUB + 4214784;  float* T3 = TT + 4214784;
    float* S4 = SUB + 4280320;  float* T4 = TT + 4280320;

    // 1. LN1 + weight prep, one launch
    ln1_wprep_kernel<<<25808, 256, 0, stream>>>(x, ln1w, ln1b, XA, XAb, XCI,
        qw, kv1w, kv2w, pw, f1w, f2w, cpw, qwt, kv1wt, kv2wt, pwt, w1t, w2t, cpwt);

    // 2. Full DWT cascade (levels 0-4), one launch
    dwt_all_kernel<<<1024, 256, 0, stream>>>(XCI, S0, S1, S2, S3, S4);

    // 3. ALL wavelet depthwise convs in one launch
    dw3x3_all_kernel<<<16784, 256, 0, stream>>>(SUB, wavw, wavs, TT);

    // 4. Full IDWT cascade (levels 4-1) + level-0 + base conv, one launch
    idwt_all_dwbase_kernel<<<1024, 256, 0, stream>>>(T4, T3, T2, T1, T0, XCI,
                                                     wbw, wbs, wbb, CIMGb);

    // 5. cp2d implicit-GEMM MFMA + fused cn -> ACATb[96:128]
    cp2d_cn_kernel<<<dim3(49, 32), 256, 0, stream>>>(CIMGb, cpwt, cpb, cnw, cnb, ACATb);

    // 6. FUSED spatial reductions + LN96 + gelu (X1P/X2P eliminated)
    sr_ln_kernel<<<3920, 256, 0, stream>>>(XA, sr1w, sr1b, an1w, an1b, X1Bb,
                                           sr2w, sr2b, an2w, an2b, X2Bb);

    // 7. merged q + kv1 + kv2 GEMMs (one launch)
    qkv_kernel<<<1691, 256, 0, stream>>>(XAb, qwt, QB, X1Bb, kv1wt, KV1, X2Bb, kv2wt, KV2);

    // 8. merged attention -> ACATb[0:96]
    attn_kernel<<<dim3(13, 8, 32), 256, 0, stream>>>(QB, KV1, KV2, ACATb);

    // 9. proj + bias + residual(x) + FUSED LN2 -> XRES fp32 + XNb bf16
    proj_ln_kernel<<<1568, 256, 0, stream>>>(ACATb, pwt, pb, x, ln2w, ln2b, XRES, XNb);

    // 10. fc1 + bias + gelu -> Hb bf16  (BK=64; proven)
    gemm_kernel<4,64,true,false,1><<<dim3(8, 1568), 256, 0, stream>>>(XNb, w1t, f1b, nullptr, Hb, 100352, 128, 512);

    // 11. fc2 + bias + residual(XRES) -> d_out fp32  (proven shape)
    gemm_kernel<4,64,false,true,0><<<dim3(2, 1568), 256, 0, stream>>>(Hb, w2t, f2b, XRES, dout, 100352, 512, 128);
}